// Round 7
// baseline (248.817 us; speedup 1.0000x reference)
//
#include <hip/hip_runtime.h>
#include <stdint.h>

typedef unsigned short u16;
typedef unsigned int   u32;
typedef __bf16 bf16x8_t __attribute__((ext_vector_type(8)));
typedef float  f32x4_t  __attribute__((ext_vector_type(4)));

#define MFMA16(a, b, c) __builtin_amdgcn_mfma_f32_16x16x32_bf16((a), (b), (c), 0, 0, 0)

__device__ __forceinline__ float bf2f(u16 u) {
    union { u32 i; float f; } c; c.i = ((u32)u) << 16; return c.f;
}
__device__ __forceinline__ u16 f2bf(float f) {
    union { float f; u32 i; } c; c.f = f;
    u32 x = c.i;
    return (u16)((x + 0x7fffu + ((x >> 16) & 1u)) >> 16);  // RNE
}
// Packed f32x2 -> bf16x2 (RNE), single instruction. S0 -> bits[15:0].
// (Guide T12 recipe, m214v22-verified operand order.)
__device__ __forceinline__ u32 cvtpk(float lo, float hi) {
    u32 r;
    asm("v_cvt_pk_bf16_f32 %0, %1, %2" : "=v"(r) : "v"(lo), "v"(hi));
    return r;
}

// Direct global->LDS DMA, 16B per lane. LDS dest must be wave-uniform base
// (HW adds lane*16); global src is per-lane (carries the XOR swizzle).
typedef const unsigned int __attribute__((address_space(1)))* gas_t;
typedef unsigned int __attribute__((address_space(3)))* las_t;
__device__ __forceinline__ void gload16(const u16* g, const u16* l) {
    __builtin_amdgcn_global_load_lds((gas_t)(const void*)g, (las_t)(void*)l, 16, 0, 0);
}

// ---------------------------------------------------------------------------
// Block-local input-dtype detection (flag=1 -> fp32 inputs).
// ---------------------------------------------------------------------------
__device__ __forceinline__ u32 detect_fp32(const u16* __restrict__ xu,
                                           int tid, int* wcnt) {
    u16 w = xu[2 * tid];
    int e = (w >> 7) & 0xff;
    int ok = (e >= 80 && e <= 160) ? 1 : 0;
    unsigned long long m = __ballot(ok);
    if ((tid & 63) == 0) wcnt[tid >> 6] = __popcll(m);
    __syncthreads();
    int cnt = wcnt[0] + wcnt[1] + wcnt[2] + wcnt[3];
    return (cnt < 160) ? 1u : 0u;
}

// ---------------------------------------------------------------------------
// Kernel W: convert W1/b1/W2/b2 to bf16 copies in workspace.
// W1/b1 rows are PERMUTED to grouped-QKV: new row h*96 + w*32 + e comes from
// original row 3*(h*32+e) + w.
// ---------------------------------------------------------------------------
__global__ __launch_bounds__(256) void conv_w(const u16* __restrict__ xu,
                                              const void* __restrict__ W1,
                                              const void* __restrict__ b1,
                                              const void* __restrict__ W2,
                                              const void* __restrict__ b2,
                                              u16* __restrict__ W1b,
                                              u16* __restrict__ b1b,
                                              u16* __restrict__ W2b,
                                              u16* __restrict__ b2b) {
    __shared__ int wcnt[4];
    u32 f = detect_fp32(xu, threadIdx.x, wcnt);
    int i = blockIdx.x * 256 + threadIdx.x;
    const int n1 = 196608, n2 = 768, n3 = 65536;
    if (i < n1) {
        int o = i >> 8, col = i & 255;
        int h = o / 96, rem = o - h * 96;
        int w = rem >> 5, e = rem & 31;
        int src = (3 * (h * 32 + e) + w) * 256 + col;
        W1b[i] = f ? f2bf(((const float*)W1)[src]) : ((const u16*)W1)[src];
    } else if (i < n1 + n2) {
        int o = i - n1;
        int h = o / 96, rem = o - h * 96;
        int w = rem >> 5, e = rem & 31;
        int src = 3 * (h * 32 + e) + w;
        b1b[o] = f ? f2bf(((const float*)b1)[src]) : ((const u16*)b1)[src];
    } else if (i < n1 + n2 + n3) {
        int li = i - n1 - n2;
        W2b[li] = f ? f2bf(((const float*)W2)[li]) : ((const u16*)W2)[li];
    } else {
        int li = i - n1 - n2 - n3;
        b2b[li] = f ? f2bf(((const float*)b2)[li]) : ((const u16*)b2)[li];
    }
}

// ---------------------------------------------------------------------------
// Kernel X: x [b][c][hw] -> xT [b*4096+hw][c] bf16 (pixel-major)
// ---------------------------------------------------------------------------
__global__ __launch_bounds__(256) void conv_x(const void* __restrict__ X,
                                              u16* __restrict__ XT) {
    __shared__ __align__(16) u16 tile[64][68];
    __shared__ int wcnt[4];
    const int tid = threadIdx.x;
    u32 f = detect_fp32((const u16*)X, tid, wcnt);
    const int b = blockIdx.z, c0 = blockIdx.y * 64, h0 = blockIdx.x * 64;
    const int col = tid & 63, rq = tid >> 6;
    if (f) {
        const float* Xf = (const float*)X;
#pragma unroll
        for (int i = 0; i < 16; i++) {
            int row = i * 4 + rq;
            tile[row][col] = f2bf(Xf[((size_t)(b * 256 + c0 + row)) * 4096 + h0 + col]);
        }
    } else {
        const u16* Xh = (const u16*)X;
#pragma unroll
        for (int i = 0; i < 16; i++) {
            int row = i * 4 + rq;
            tile[row][col] = Xh[((size_t)(b * 256 + c0 + row)) * 4096 + h0 + col];
        }
    }
    __syncthreads();
#pragma unroll
    for (int i = 0; i < 16; i++) {
        int row = i * 4 + rq;
        XT[((size_t)(b * 4096 + h0 + row)) * 256 + c0 + col] = tile[col][row];
    }
}

// ---------------------------------------------------------------------------
// Kernel 1: qkv = xT @ W1^T + b1 with 96-wide n-tiles (= one head exactly).
// W1b rows grouped [Q|K|V] per head -> vectorizable repack epilogue.
// ---------------------------------------------------------------------------
__global__ __launch_bounds__(256) void gemm_qkv(const u16* __restrict__ XT,
                                                const u16* __restrict__ W1,
                                                const u16* __restrict__ b1,
                                                u16* __restrict__ Q2,
                                                u16* __restrict__ K2,
                                                u16* __restrict__ V2) {
    __shared__ __align__(16) u16 smem[128 * 64 + 96 * 64];  // 28 KB
    u16* sA = smem;
    u16* sB = smem + 128 * 64;
    u16* Cs = smem;  // reused after barrier: 128 x 104 = 13312 <= 14336

    const int tid  = threadIdx.x;
    const int lane = tid & 63, wave = tid >> 6;
    const int quad = lane >> 4, l16 = lane & 15;
    const int wm = wave * 32;
    const int bx = blockIdx.x;
    const int bm = (bx >> 6) * 8 + (bx & 7);  // 512 m-tiles
    const int h  = (bx >> 3) & 7;             // 8 heads
    const int o_base = h * 96;

    f32x4_t acc[2][6];
    const f32x4_t zz = {0.f, 0.f, 0.f, 0.f};
#pragma unroll
    for (int i = 0; i < 2; i++)
#pragma unroll
        for (int j = 0; j < 6; j++) acc[i][j] = zz;

    // per-lane pre-swizzled staging addresses (k-invariant, hoisted)
    const int sub = lane >> 3;              // row-within-8
    const int cpw = (lane & 7) ^ sub;       // global chunk for this lane
    const u16* gA[4]; const u16* gB[3];
    const u16* lA[4]; const u16* lB[3];
#pragma unroll
    for (int i = 0; i < 4; i++) {
        int r8 = (wave * 4 + i) * 8;
        gA[i] = XT + ((size_t)(bm * 128 + r8 + sub)) * 256 + cpw * 8;
        lA[i] = sA + r8 * 64;               // wave-uniform LDS base
    }
#pragma unroll
    for (int i = 0; i < 3; i++) {
        int r8 = (wave * 3 + i) * 8;
        gB[i] = W1 + ((size_t)(o_base + r8 + sub)) * 256 + cpw * 8;
        lB[i] = sB + r8 * 64;
    }

    for (int kt = 0; kt < 256; kt += 64) {
        __syncthreads();
#pragma unroll
        for (int i = 0; i < 4; i++) gload16(gA[i] + kt, lA[i]);
#pragma unroll
        for (int i = 0; i < 3; i++) gload16(gB[i] + kt, lB[i]);
        __syncthreads();  // implicit vmcnt(0) drains the DMA
#pragma unroll
        for (int ks = 0; ks < 2; ks++) {
            bf16x8_t af[2], bg[6];
#pragma unroll
            for (int i = 0; i < 2; i++) {
                int row = wm + i * 16 + l16;
                int cp = (ks * 4 + quad) ^ (row & 7);
                af[i] = *(const bf16x8_t*)(sA + row * 64 + cp * 8);
            }
#pragma unroll
            for (int j = 0; j < 6; j++) {
                int row = j * 16 + l16;
                int cp = (ks * 4 + quad) ^ (row & 7);
                bg[j] = *(const bf16x8_t*)(sB + row * 64 + cp * 8);
            }
#pragma unroll
            for (int i = 0; i < 2; i++)
#pragma unroll
                for (int j = 0; j < 6; j++)
                    acc[i][j] = MFMA16(af[i], bg[j], acc[i][j]);
        }
    }

    // ---- epilogue: bias + bf16 -> Cs[128 m][col 96] (stride 104) ----
    __syncthreads();
#pragma unroll
    for (int j = 0; j < 6; j++) {
        float bias = bf2f(b1[o_base + j * 16 + l16]);
#pragma unroll
        for (int i = 0; i < 2; i++) {
            int m = wm + i * 16 + quad * 4;
#pragma unroll
            for (int r = 0; r < 4; r++)
                Cs[(m + r) * 104 + j * 16 + l16] = f2bf(acc[i][j][r] + bias);
        }
    }
    __syncthreads();

    // ---- repack: grouped cols -> vector reads; pixel-major [b][h][hw][e] ----
    const int b = bm >> 5;
    const int hw0 = (bm & 31) * 128;
    const size_t hb = ((size_t)(b * 8 + h)) * 4096;
#pragma unroll
    for (int it = 0; it < 2; it++) {
        int u = it * 256 + tid;
        int px = u >> 2, ch = u & 3;
        size_t gaddr = (hb + hw0 + px) * 32 + ch * 8;
        *(uint4*)(Q2 + gaddr) = *(const uint4*)(Cs + px * 104 +      ch * 8);
        *(uint4*)(K2 + gaddr) = *(const uint4*)(Cs + px * 104 + 32 + ch * 8);
        *(uint4*)(V2 + gaddr) = *(const uint4*)(Cs + px * 104 + 64 + ch * 8);
    }
}

// ---------------------------------------------------------------------------
// Kernel 2: windowed overlapping attention (Q 8x8, K/V 12x12 zero-padded).
// Q straight to registers.  LDS 32256 B -> 5 blocks/CU.
// Max-subtraction KEPT (overflow-safe for any input scale; r5 lesson).
// P->bf16 and O->bf16 via v_cvt_pk_bf16_f32 pairs (1 inst per 2 values).
// ---------------------------------------------------------------------------
__global__ __launch_bounds__(256) void attn_kernel(const u16* __restrict__ Q2,
                                                   const u16* __restrict__ K2,
                                                   const u16* __restrict__ V2,
                                                   u16* __restrict__ Op) {
    __shared__ __align__(16) u16 smem[16128];  // 32256 B
    u16* Ks = smem;               // [k][e]    stride 40   (dead after QK^T)
    u16* Ps = smem;               // [q][k]    stride 168  (overlay)
    u16* Vt = smem + 10752;       // [e][k]    stride 168, swizzled cols

    const int tid  = threadIdx.x;
    const int lane = tid & 63, wave = tid >> 6;
    const int quad = lane >> 4, l16 = lane & 15;
    const int win = blockIdx.x, head = blockIdx.y, b = blockIdx.z;
    const int wi = win >> 3, wj = win & 7;
    const size_t hb = ((size_t)(b * 8 + head)) * 4096;

    // ---- Q straight to register: row wave*16+l16, chunk quad (16B) ----
    bf16x8_t aF;
    {
        int px = wave * 16 + l16;
        int qy = px >> 3, qx = px & 7;
        aF = *(const bf16x8_t*)(Q2 + (hb + (wi * 8 + qy) * 64 + wj * 8 + qx) * 32 + quad * 8);
    }
    // ---- stage K + V (merged, one addr calc); V transposed w/ swizzle ----
    for (int u = tid; u < 576; u += 256) {
        int px = u >> 2, ch = u & 3;
        int py = px / 12, kx = px - py * 12;
        int gy = wi * 8 - 2 + py, gx = wj * 8 - 2 + kx;
        uint4 kv = make_uint4(0, 0, 0, 0), vv = make_uint4(0, 0, 0, 0);
        if (gy >= 0 && gy < 64 && gx >= 0 && gx < 64) {
            size_t off = (hb + gy * 64 + gx) * 32 + ch * 8;
            kv = *(const uint4*)(K2 + off);
            vv = *(const uint4*)(V2 + off);
        }
        *(uint4*)(Ks + px * 40 + ch * 8) = kv;
        int colp = px ^ (ch << 3);
        int e0 = ch * 8;
        u32 w0[4] = {vv.x, vv.y, vv.z, vv.w};
#pragma unroll
        for (int p = 0; p < 4; p++) {
            Vt[(e0 + 2 * p    ) * 168 + colp] = (u16)(w0[p] & 0xffff);
            Vt[(e0 + 2 * p + 1) * 168 + colp] = (u16)(w0[p] >> 16);
        }
    }
    // ---- Vt pad cols 144..159 (swizzled addresses) ----
    for (int t = tid; t < 512; t += 256) {
        int e = t >> 4, cl = 144 + (t & 15);
        Vt[e * 168 + (cl ^ ((e >> 3) << 3))] = 0;
    }
    __syncthreads();

    // ---- scores: S_raw = Q K^T (wave w owns q rows 16w..16w+15) ----
    float s[9][4];
    {
        const f32x4_t zz = {0.f, 0.f, 0.f, 0.f};
#pragma unroll
        for (int j = 0; j < 9; j++) {
            bf16x8_t bF = *(const bf16x8_t*)(Ks + (j * 16 + l16) * 40 + quad * 8);
            f32x4_t d = MFMA16(aF, bF, zz);
#pragma unroll
            for (int r = 0; r < 4; r++) s[j][r] = d[r];
        }
    }
    // ---- row max on raw scores (scale folded into exp arg) ----
    float mx[4] = {-1e30f, -1e30f, -1e30f, -1e30f};
#pragma unroll
    for (int j = 0; j < 9; j++)
#pragma unroll
        for (int r = 0; r < 4; r++) mx[r] = fmaxf(mx[r], s[j][r]);
#pragma unroll
    for (int off = 1; off < 16; off <<= 1)
#pragma unroll
        for (int r = 0; r < 4; r++) mx[r] = fmaxf(mx[r], __shfl_xor(mx[r], off, 16));

    __syncthreads();  // Ks fully consumed by all waves; Ps overlay begins

    // ---- Ps pad cols 144..159 for this wave's 16 rows (one b64/lane) ----
    *(unsigned long long*)(Ps + (wave * 16 + l16) * 168 + 144 + quad * 4) = 0ULL;

    const float scale = 0.17677669529663687f;  // 1/sqrt(32)
    float msc[4];
#pragma unroll
    for (int r = 0; r < 4; r++) msc[r] = mx[r] * scale;
    float sm[4] = {0.f, 0.f, 0.f, 0.f};
#pragma unroll
    for (int j = 0; j < 9; j++) {
        float p0 = __expf(fmaf(s[j][0], scale, -msc[0]));
        float p1 = __expf(fmaf(s[j][1], scale, -msc[1]));
        float p2 = __expf(fmaf(s[j][2], scale, -msc[2]));
        float p3 = __expf(fmaf(s[j][3], scale, -msc[3]));
        sm[0] += p0; sm[1] += p1; sm[2] += p2; sm[3] += p3;
        u32 a = cvtpk(p0, p1);
        u32 c = cvtpk(p2, p3);
        u16* base = Ps + (wave * 16 + quad * 4) * 168 + j * 16 + l16;
        base[0]   = (u16)a;
        base[168] = (u16)(a >> 16);
        base[336] = (u16)c;
        base[504] = (u16)(c >> 16);
    }
#pragma unroll
    for (int off = 1; off < 16; off <<= 1)
#pragma unroll
        for (int r = 0; r < 4; r++) sm[r] += __shfl_xor(sm[r], off, 16);

    __syncthreads();  // fence Ps u16 stores vs bf16x8 loads (all waves)

    // ---- O = P V (K-dim padded to 160 with zeros) ----
    f32x4_t oa[2];
    oa[0] = (f32x4_t){0.f, 0.f, 0.f, 0.f};
    oa[1] = (f32x4_t){0.f, 0.f, 0.f, 0.f};
#pragma unroll
    for (int kk = 0; kk < 5; kk++) {
        bf16x8_t aP = *(const bf16x8_t*)(Ps + (wave * 16 + l16) * 168 + kk * 32 + quad * 8);
#pragma unroll
        for (int nt = 0; nt < 2; nt++) {
            int er = nt * 16 + l16;
            int sw = (er >> 3) << 3;
            bf16x8_t bV = *(const bf16x8_t*)(Vt + er * 168 + ((kk * 32 + quad * 8) ^ sw));
            oa[nt] = MFMA16(aP, bV, oa[nt]);
        }
    }
    float inv[4];
#pragma unroll
    for (int r = 0; r < 4; r++) inv[r] = 1.0f / sm[r];  // sm >= 1 (max term)
#pragma unroll
    for (int nt = 0; nt < 2; nt++) {
        int e = nt * 16 + l16;
#pragma unroll
        for (int rp = 0; rp < 2; rp++) {
            int r = rp * 2;
            u32 a = cvtpk(oa[nt][r] * inv[r], oa[nt][r + 1] * inv[r + 1]);
            int q0 = wave * 16 + quad * 4 + r;
            int qy = q0 >> 3, qx = q0 & 7;  // q0&7 in {0,2,4,6}: rows share qy
            size_t pix = (size_t)(b * 4096) + (wi * 8 + qy) * 64 + (wj * 8 + qx);
            Op[pix * 256 + head * 32 + e]       = (u16)a;
            Op[(pix + 1) * 256 + head * 32 + e] = (u16)(a >> 16);
        }
    }
}

// ---------------------------------------------------------------------------
// Shared 128x128 GEMM mainloop (used by gemm_out).
// ---------------------------------------------------------------------------
__device__ __forceinline__ void gemm_loop(const u16* __restrict__ A,
                                          const u16* __restrict__ B,
                                          int K, int bm, int bn,
                                          u16* sA, u16* sB, f32x4_t acc[4][4]) {
    const int tid  = threadIdx.x;
    const int lane = tid & 63, wave = tid >> 6;
    const int quad = lane >> 4, l16 = lane & 15;
    const int wm = (wave >> 1) * 64, wn = (wave & 1) * 64;

    const int sub = lane >> 3;
    const int cpw = (lane & 7) ^ sub;
    const u16* gA[4]; const u16* gB[4];
    const u16* lA[4]; const u16* lB[4];
#pragma unroll
    for (int i = 0; i < 4; i++) {
        int r8 = (wave * 4 + i) * 8;
        gA[i] = A + ((size_t)(bm * 128 + r8 + sub)) * K + cpw * 8;
        gB[i] = B + ((size_t)(bn * 128 + r8 + sub)) * K + cpw * 8;
        lA[i] = sA + r8 * 64;
        lB[i] = sB + r8 * 64;
    }

    for (int kt = 0; kt < K; kt += 64) {
        __syncthreads();
#pragma unroll
        for (int i = 0; i < 4; i++) gload16(gA[i] + kt, lA[i]);
#pragma unroll
        for (int i = 0; i < 4; i++) gload16(gB[i] + kt, lB[i]);
        __syncthreads();
#pragma unroll
        for (int ks = 0; ks < 2; ks++) {
            bf16x8_t af[4], bg[4];
#pragma unroll
            for (int i = 0; i < 4; i++) {
                int row = wm + i * 16 + l16;
                int cp = (ks * 4 + quad) ^ (row & 7);
                af[i] = *(const bf16x8_t*)(sA + row * 64 + cp * 8);
            }
#pragma unroll
            for (int j = 0; j < 4; j++) {
                int row = wn + j * 16 + l16;
                int cp = (ks * 4 + quad) ^ (row & 7);
                bg[j] = *(const bf16x8_t*)(sB + row * 64 + cp * 8);
            }
#pragma unroll
            for (int i = 0; i < 4; i++)
#pragma unroll
                for (int j = 0; j < 4; j++)
                    acc[i][j] = MFMA16(af[i], bg[j], acc[i][j]);
        }
    }
}

// ---------------------------------------------------------------------------
// Kernel 3: y = attn @ W2^T + b2 -> d_out [b][c'][hw]; fp32 if fp32 inputs.
// ---------------------------------------------------------------------------
__global__ __launch_bounds__(256) void gemm_out(const u16* __restrict__ xu,
                                                const u16* __restrict__ Ap,
                                                const u16* __restrict__ W2,
                                                const u16* __restrict__ b2,
                                                void* __restrict__ Y) {
    __shared__ __align__(16) u16 sA[128 * 64];
    __shared__ __align__(16) u16 sB[128 * 64];
    __shared__ int wcnt[4];
    const u32 out_f32 = detect_fp32(xu, threadIdx.x, wcnt);

    f32x4_t acc[4][4];
    const f32x4_t zz = {0.f, 0.f, 0.f, 0.f};
#pragma unroll
    for (int i = 0; i < 4; i++)
#pragma unroll
        for (int j = 0; j < 4; j++) acc[i][j] = zz;

    const int bm = blockIdx.x, bn = blockIdx.y;
    gemm_loop(Ap, W2, 256, bm, bn, sA, sB, acc);

    const int lane = threadIdx.x & 63, wave = threadIdx.x >> 6;
    const int quad = lane >> 4, l16 = lane & 15;
    const int wm = (wave >> 1) * 64, wn = (wave & 1) * 64;
    const int b = bm >> 5;
    const int hw0 = (bm & 31) * 128;
#pragma unroll
    for (int j = 0; j < 4; j++) {
        int o = bn * 128 + wn + j * 16 + l16;
        float bias = bf2f(b2[o]);
        size_t base = ((size_t)(b * 256 + o)) * 4096;
        if (out_f32) {
            float* Yf = (float*)Y;
#pragma unroll
            for (int i = 0; i < 4; i++) {
                int m0 = hw0 + wm + i * 16 + quad * 4;
                f32x4_t ov;
#pragma unroll
                for (int r = 0; r < 4; r++) ov[r] = acc[i][j][r] + bias;
                *(f32x4_t*)(Yf + base + m0) = ov;
            }
        } else {
            u16* Yh = (u16*)Y;
#pragma unroll
            for (int i = 0; i < 4; i++) {
                int m0 = hw0 + wm + i * 16 + quad * 4;
                u32 lo = cvtpk(acc[i][j][0] + bias, acc[i][j][1] + bias);
                u32 hi = cvtpk(acc[i][j][2] + bias, acc[i][j][3] + bias);
                u32* d32 = (u32*)(Yh + base + m0);
                d32[0] = lo; d32[1] = hi;
            }
        }
    }
}

// ---------------------------------------------------------------------------
extern "C" void kernel_launch(void* const* d_in, const int* in_sizes, int n_in,
                              void* d_out, int out_size, void* d_ws, size_t ws_size,
                              hipStream_t stream) {
    (void)in_sizes; (void)n_in; (void)out_size; (void)ws_size;
    const void* x  = d_in[0];
    const void* W1 = d_in[1];
    const void* b1 = d_in[2];
    const void* W2 = d_in[3];
    const void* b2 = d_in[4];
    const u16* xu = (const u16*)x;

    char* ws = (char*)d_ws;
    const size_t MB32 = (size_t)32 * 1024 * 1024;
    u16* xT  = (u16*)(ws);              // 32 MiB; reused as attention output Op
    u16* Q2  = (u16*)(ws + MB32);       // 32 MiB  [b][head][hw][e]
    u16* K2  = (u16*)(ws + 2 * MB32);   // 32 MiB
    u16* V2  = (u16*)(ws + 3 * MB32);   // 32 MiB
    u16* W1b = (u16*)(ws + 4 * MB32);   // 196608 elems (grouped-QKV rows)
    u16* b1b = W1b + 196608;            // 768
    u16* W2b = b1b + 768;               // 65536
    u16* b2b = W2b + 65536;             // 256
    u16* Op  = xT;                      // overlay: xT dead after gemm_qkv

    conv_w  <<<1028, 256, 0, stream>>>(xu, W1, b1, W2, b2, W1b, b1b, W2b, b2b);
    conv_x  <<<dim3(64, 4, 16), 256, 0, stream>>>(x, xT);
    gemm_qkv<<<4096, 256, 0, stream>>>(xT, W1b, b1b, Q2, K2, V2);
    attn_kernel<<<dim3(64, 8, 16), 256, 0, stream>>>(Q2, K2, V2, Op);
    gemm_out<<<dim3(512, 2), 256, 0, stream>>>(xu, Op, W2b, b2b, d_out);
}

// Round 9
// 243.571 us; speedup vs baseline: 1.0215x; 1.0215x over previous
//
#include <hip/hip_runtime.h>
#include <stdint.h>

typedef unsigned short u16;
typedef unsigned int   u32;
typedef __bf16 bf16x8_t __attribute__((ext_vector_type(8)));
typedef float  f32x4_t  __attribute__((ext_vector_type(4)));

#define MFMA16(a, b, c) __builtin_amdgcn_mfma_f32_16x16x32_bf16((a), (b), (c), 0, 0, 0)

__device__ __forceinline__ float bf2f(u16 u) {
    union { u32 i; float f; } c; c.i = ((u32)u) << 16; return c.f;
}
__device__ __forceinline__ u16 f2bf(float f) {
    union { float f; u32 i; } c; c.f = f;
    u32 x = c.i;
    return (u16)((x + 0x7fffu + ((x >> 16) & 1u)) >> 16);  // RNE
}
// Packed f32x2 -> bf16x2 (RNE), single instruction. S0 -> bits[15:0].
__device__ __forceinline__ u32 cvtpk(float lo, float hi) {
    u32 r;
    asm("v_cvt_pk_bf16_f32 %0, %1, %2" : "=v"(r) : "v"(lo), "v"(hi));
    return r;
}
// 2^x via v_exp_f32 (builtin avoids glibc __exp2f macro collision).
__device__ __forceinline__ float exp2g(float x) {
    return __builtin_amdgcn_exp2f(x);
}

// Direct global->LDS DMA, 16B per lane. LDS dest must be wave-uniform base
// (HW adds lane*16); global src is per-lane (carries the XOR swizzle).
typedef const unsigned int __attribute__((address_space(1)))* gas_t;
typedef unsigned int __attribute__((address_space(3)))* las_t;
__device__ __forceinline__ void gload16(const u16* g, const u16* l) {
    __builtin_amdgcn_global_load_lds((gas_t)(const void*)g, (las_t)(void*)l, 16, 0, 0);
}

// ---------------------------------------------------------------------------
// Block-local input-dtype detection (flag=1 -> fp32 inputs).
// ---------------------------------------------------------------------------
__device__ __forceinline__ u32 detect_fp32(const u16* __restrict__ xu,
                                           int tid, int* wcnt) {
    u16 w = xu[2 * tid];
    int e = (w >> 7) & 0xff;
    int ok = (e >= 80 && e <= 160) ? 1 : 0;
    unsigned long long m = __ballot(ok);
    if ((tid & 63) == 0) wcnt[tid >> 6] = __popcll(m);
    __syncthreads();
    int cnt = wcnt[0] + wcnt[1] + wcnt[2] + wcnt[3];
    return (cnt < 160) ? 1u : 0u;
}

// ---------------------------------------------------------------------------
// Kernel W: convert W1/b1/W2/b2 to bf16 copies in workspace.
// W1/b1 rows are PERMUTED to grouped-QKV: new row h*96 + w*32 + e comes from
// original row 3*(h*32+e) + w.
// ---------------------------------------------------------------------------
__global__ __launch_bounds__(256) void conv_w(const u16* __restrict__ xu,
                                              const void* __restrict__ W1,
                                              const void* __restrict__ b1,
                                              const void* __restrict__ W2,
                                              const void* __restrict__ b2,
                                              u16* __restrict__ W1b,
                                              u16* __restrict__ b1b,
                                              u16* __restrict__ W2b,
                                              u16* __restrict__ b2b) {
    __shared__ int wcnt[4];
    u32 f = detect_fp32(xu, threadIdx.x, wcnt);
    int i = blockIdx.x * 256 + threadIdx.x;
    const int n1 = 196608, n2 = 768, n3 = 65536;
    if (i < n1) {
        int o = i >> 8, col = i & 255;
        int h = o / 96, rem = o - h * 96;
        int w = rem >> 5, e = rem & 31;
        int src = (3 * (h * 32 + e) + w) * 256 + col;
        W1b[i] = f ? f2bf(((const float*)W1)[src]) : ((const u16*)W1)[src];
    } else if (i < n1 + n2) {
        int o = i - n1;
        int h = o / 96, rem = o - h * 96;
        int w = rem >> 5, e = rem & 31;
        int src = 3 * (h * 32 + e) + w;
        b1b[o] = f ? f2bf(((const float*)b1)[src]) : ((const u16*)b1)[src];
    } else if (i < n1 + n2 + n3) {
        int li = i - n1 - n2;
        W2b[li] = f ? f2bf(((const float*)W2)[li]) : ((const u16*)W2)[li];
    } else {
        int li = i - n1 - n2 - n3;
        b2b[li] = f ? f2bf(((const float*)b2)[li]) : ((const u16*)b2)[li];
    }
}

// ---------------------------------------------------------------------------
// Kernel X: x [b][c][hw] -> xT [b*4096+hw][c] bf16 (pixel-major)
// ---------------------------------------------------------------------------
__global__ __launch_bounds__(256) void conv_x(const void* __restrict__ X,
                                              u16* __restrict__ XT) {
    __shared__ __align__(16) u16 tile[64][68];
    __shared__ int wcnt[4];
    const int tid = threadIdx.x;
    u32 f = detect_fp32((const u16*)X, tid, wcnt);
    const int b = blockIdx.z, c0 = blockIdx.y * 64, h0 = blockIdx.x * 64;
    const int col = tid & 63, rq = tid >> 6;
    if (f) {
        const float* Xf = (const float*)X;
#pragma unroll
        for (int i = 0; i < 16; i++) {
            int row = i * 4 + rq;
            tile[row][col] = f2bf(Xf[((size_t)(b * 256 + c0 + row)) * 4096 + h0 + col]);
        }
    } else {
        const u16* Xh = (const u16*)X;
#pragma unroll
        for (int i = 0; i < 16; i++) {
            int row = i * 4 + rq;
            tile[row][col] = Xh[((size_t)(b * 256 + c0 + row)) * 4096 + h0 + col];
        }
    }
    __syncthreads();
#pragma unroll
    for (int i = 0; i < 16; i++) {
        int row = i * 4 + rq;
        XT[((size_t)(b * 4096 + h0 + row)) * 256 + c0 + col] = tile[col][row];
    }
}

// ---------------------------------------------------------------------------
// Kernel 1: qkv = xT @ W1^T + b1 with 96-wide n-tiles (= one head exactly).
// W1b rows grouped [Q|K|V] per head -> vectorizable repack epilogue.
// ---------------------------------------------------------------------------
__global__ __launch_bounds__(256) void gemm_qkv(const u16* __restrict__ XT,
                                                const u16* __restrict__ W1,
                                                const u16* __restrict__ b1,
                                                u16* __restrict__ Q2,
                                                u16* __restrict__ K2,
                                                u16* __restrict__ V2) {
    __shared__ __align__(16) u16 smem[128 * 64 + 96 * 64];  // 28 KB
    u16* sA = smem;
    u16* sB = smem + 128 * 64;
    u16* Cs = smem;  // reused after barrier: 128 x 104 = 13312 <= 14336

    const int tid  = threadIdx.x;
    const int lane = tid & 63, wave = tid >> 6;
    const int quad = lane >> 4, l16 = lane & 15;
    const int wm = wave * 32;
    const int bx = blockIdx.x;
    const int bm = (bx >> 6) * 8 + (bx & 7);  // 512 m-tiles
    const int h  = (bx >> 3) & 7;             // 8 heads
    const int o_base = h * 96;

    f32x4_t acc[2][6];
    const f32x4_t zz = {0.f, 0.f, 0.f, 0.f};
#pragma unroll
    for (int i = 0; i < 2; i++)
#pragma unroll
        for (int j = 0; j < 6; j++) acc[i][j] = zz;

    // per-lane pre-swizzled staging addresses (k-invariant, hoisted)
    const int sub = lane >> 3;              // row-within-8
    const int cpw = (lane & 7) ^ sub;       // global chunk for this lane
    const u16* gA[4]; const u16* gB[3];
    const u16* lA[4]; const u16* lB[3];
#pragma unroll
    for (int i = 0; i < 4; i++) {
        int r8 = (wave * 4 + i) * 8;
        gA[i] = XT + ((size_t)(bm * 128 + r8 + sub)) * 256 + cpw * 8;
        lA[i] = sA + r8 * 64;               // wave-uniform LDS base
    }
#pragma unroll
    for (int i = 0; i < 3; i++) {
        int r8 = (wave * 3 + i) * 8;
        gB[i] = W1 + ((size_t)(o_base + r8 + sub)) * 256 + cpw * 8;
        lB[i] = sB + r8 * 64;
    }

    for (int kt = 0; kt < 256; kt += 64) {
        __syncthreads();
#pragma unroll
        for (int i = 0; i < 4; i++) gload16(gA[i] + kt, lA[i]);
#pragma unroll
        for (int i = 0; i < 3; i++) gload16(gB[i] + kt, lB[i]);
        __syncthreads();  // implicit vmcnt(0) drains the DMA
#pragma unroll
        for (int ks = 0; ks < 2; ks++) {
            bf16x8_t af[2], bg[6];
#pragma unroll
            for (int i = 0; i < 2; i++) {
                int row = wm + i * 16 + l16;
                int cp = (ks * 4 + quad) ^ (row & 7);
                af[i] = *(const bf16x8_t*)(sA + row * 64 + cp * 8);
            }
#pragma unroll
            for (int j = 0; j < 6; j++) {
                int row = j * 16 + l16;
                int cp = (ks * 4 + quad) ^ (row & 7);
                bg[j] = *(const bf16x8_t*)(sB + row * 64 + cp * 8);
            }
#pragma unroll
            for (int i = 0; i < 2; i++)
#pragma unroll
                for (int j = 0; j < 6; j++)
                    acc[i][j] = MFMA16(af[i], bg[j], acc[i][j]);
        }
    }

    // ---- epilogue: bias + bf16 -> Cs[128 m][col 96] (stride 104) ----
    __syncthreads();
#pragma unroll
    for (int j = 0; j < 6; j++) {
        float bias = bf2f(b1[o_base + j * 16 + l16]);
#pragma unroll
        for (int i = 0; i < 2; i++) {
            int m = wm + i * 16 + quad * 4;
#pragma unroll
            for (int r = 0; r < 4; r++)
                Cs[(m + r) * 104 + j * 16 + l16] = f2bf(acc[i][j][r] + bias);
        }
    }
    __syncthreads();

    // ---- repack: grouped cols -> vector reads; pixel-major [b][h][hw][e] ----
    const int b = bm >> 5;
    const int hw0 = (bm & 31) * 128;
    const size_t hb = ((size_t)(b * 8 + h)) * 4096;
#pragma unroll
    for (int it = 0; it < 2; it++) {
        int u = it * 256 + tid;
        int px = u >> 2, ch = u & 3;
        size_t gaddr = (hb + hw0 + px) * 32 + ch * 8;
        *(uint4*)(Q2 + gaddr) = *(const uint4*)(Cs + px * 104 +      ch * 8);
        *(uint4*)(K2 + gaddr) = *(const uint4*)(Cs + px * 104 + 32 + ch * 8);
        *(uint4*)(V2 + gaddr) = *(const uint4*)(Cs + px * 104 + 64 + ch * 8);
    }
}

// ---------------------------------------------------------------------------
// Kernel 2: windowed overlapping attention (Q 8x8, K/V 12x12 zero-padded).
// Q straight to registers.  LDS 32256 B -> 5 blocks/CU.
// Max-subtraction KEPT (overflow-safe for any input scale; r5/r6 lesson).
// exp via v_exp_f32 (2^x) with log2e folded into scale.
// Row-max as v_max3 chains.  PV computed OPERAND-SWAPPED: O^T = mfma(V^T, P)
// -> lane holds 4 consecutive e for one q -> uint2 epilogue stores; one
// division per thread (denominator fetched via cross-quad shuffle).
// ---------------------------------------------------------------------------
__global__ __launch_bounds__(256) void attn_kernel(const u16* __restrict__ Q2,
                                                   const u16* __restrict__ K2,
                                                   const u16* __restrict__ V2,
                                                   u16* __restrict__ Op) {
    __shared__ __align__(16) u16 smem[16128];  // 32256 B
    u16* Ks = smem;               // [k][e]    stride 40   (dead after QK^T)
    u16* Ps = smem;               // [q][k]    stride 168  (overlay)
    u16* Vt = smem + 10752;       // [e][k]    stride 168, swizzled cols

    const int tid  = threadIdx.x;
    const int lane = tid & 63, wave = tid >> 6;
    const int quad = lane >> 4, l16 = lane & 15;
    const int win = blockIdx.x, head = blockIdx.y, b = blockIdx.z;
    const int wi = win >> 3, wj = win & 7;
    const size_t hb = ((size_t)(b * 8 + head)) * 4096;

    // ---- Q straight to register: row wave*16+l16, chunk quad (16B) ----
    bf16x8_t aF;
    {
        int px = wave * 16 + l16;
        int qy = px >> 3, qx = px & 7;
        aF = *(const bf16x8_t*)(Q2 + (hb + (wi * 8 + qy) * 64 + wj * 8 + qx) * 32 + quad * 8);
    }
    // ---- stage K + V (merged, one addr calc); V transposed w/ swizzle ----
    for (int u = tid; u < 576; u += 256) {
        int px = u >> 2, ch = u & 3;
        int py = px / 12, kx = px - py * 12;
        int gy = wi * 8 - 2 + py, gx = wj * 8 - 2 + kx;
        uint4 kv = make_uint4(0, 0, 0, 0), vv = make_uint4(0, 0, 0, 0);
        if (gy >= 0 && gy < 64 && gx >= 0 && gx < 64) {
            size_t off = (hb + gy * 64 + gx) * 32 + ch * 8;
            kv = *(const uint4*)(K2 + off);
            vv = *(const uint4*)(V2 + off);
        }
        *(uint4*)(Ks + px * 40 + ch * 8) = kv;
        int colp = px ^ (ch << 3);
        int e0 = ch * 8;
        u32 w0[4] = {vv.x, vv.y, vv.z, vv.w};
#pragma unroll
        for (int p = 0; p < 4; p++) {
            Vt[(e0 + 2 * p    ) * 168 + colp] = (u16)(w0[p] & 0xffff);
            Vt[(e0 + 2 * p + 1) * 168 + colp] = (u16)(w0[p] >> 16);
        }
    }
    // ---- Vt pad cols 144..159 (swizzled addresses) ----
    for (int t = tid; t < 512; t += 256) {
        int e = t >> 4, cl = 144 + (t & 15);
        Vt[e * 168 + (cl ^ ((e >> 3) << 3))] = 0;
    }
    __syncthreads();

    // ---- scores: S_raw = Q K^T (wave w owns q rows 16w..16w+15) ----
    float s[9][4];
    {
        const f32x4_t zz = {0.f, 0.f, 0.f, 0.f};
#pragma unroll
        for (int j = 0; j < 9; j++) {
            bf16x8_t bF = *(const bf16x8_t*)(Ks + (j * 16 + l16) * 40 + quad * 8);
            f32x4_t d = MFMA16(aF, bF, zz);
#pragma unroll
            for (int r = 0; r < 4; r++) s[j][r] = d[r];
        }
    }
    // ---- row max (v_max3 chains) + 16-lane butterfly ----
    float mx[4];
#pragma unroll
    for (int r = 0; r < 4; r++) {
        float a = fmaxf(fmaxf(s[0][r], s[1][r]), s[2][r]);
        a = fmaxf(fmaxf(a, s[3][r]), s[4][r]);
        a = fmaxf(fmaxf(a, s[5][r]), s[6][r]);
        a = fmaxf(fmaxf(a, s[7][r]), s[8][r]);
        mx[r] = a;
    }
#pragma unroll
    for (int off = 1; off < 16; off <<= 1)
#pragma unroll
        for (int r = 0; r < 4; r++) mx[r] = fmaxf(mx[r], __shfl_xor(mx[r], off, 16));

    __syncthreads();  // Ks fully consumed by all waves; Ps overlay begins

    // ---- Ps pad cols 144..159 for this wave's 16 rows (one b64/lane) ----
    *(unsigned long long*)(Ps + (wave * 16 + l16) * 168 + 144 + quad * 4) = 0ULL;

    const float scale2 = 0.2550348632705143f;  // log2(e)/sqrt(32)
    float msc[4];
#pragma unroll
    for (int r = 0; r < 4; r++) msc[r] = mx[r] * scale2;
    float sm[4] = {0.f, 0.f, 0.f, 0.f};
#pragma unroll
    for (int j = 0; j < 9; j++) {
        float p0 = exp2g(fmaf(s[j][0], scale2, -msc[0]));
        float p1 = exp2g(fmaf(s[j][1], scale2, -msc[1]));
        float p2 = exp2g(fmaf(s[j][2], scale2, -msc[2]));
        float p3 = exp2g(fmaf(s[j][3], scale2, -msc[3]));
        sm[0] += p0; sm[1] += p1; sm[2] += p2; sm[3] += p3;
        u32 a = cvtpk(p0, p1);
        u32 c = cvtpk(p2, p3);
        u16* base = Ps + (wave * 16 + quad * 4) * 168 + j * 16 + l16;
        base[0]   = (u16)a;
        base[168] = (u16)(a >> 16);
        base[336] = (u16)c;
        base[504] = (u16)(c >> 16);
    }
#pragma unroll
    for (int off = 1; off < 16; off <<= 1)
#pragma unroll
        for (int r = 0; r < 4; r++) sm[r] += __shfl_xor(sm[r], off, 16);

    __syncthreads();  // fence Ps u16 stores vs bf16x8 loads (all waves)

    // ---- O^T = V^T P^T via operand-swapped MFMA (same fragment loads) ----
    f32x4_t ob[2];
    ob[0] = (f32x4_t){0.f, 0.f, 0.f, 0.f};
    ob[1] = (f32x4_t){0.f, 0.f, 0.f, 0.f};
#pragma unroll
    for (int kk = 0; kk < 5; kk++) {
        bf16x8_t aP = *(const bf16x8_t*)(Ps + (wave * 16 + l16) * 168 + kk * 32 + quad * 8);
#pragma unroll
        for (int nt = 0; nt < 2; nt++) {
            int er = nt * 16 + l16;
            int sw = (er >> 3) << 3;
            bf16x8_t bV = *(const bf16x8_t*)(Vt + er * 168 + ((kk * 32 + quad * 8) ^ sw));
            ob[nt] = MFMA16(bV, aP, ob[nt]);  // D[e_local][q]: row=quad*4+r, col=l16
        }
    }
    // denominator for q-row l16 lives in quad l16>>2, slot l16&3
    {
        int srcl = (l16 >> 2) * 16;
        float d0 = __shfl(sm[0], srcl);
        float d1 = __shfl(sm[1], srcl);
        float d2 = __shfl(sm[2], srcl);
        float d3 = __shfl(sm[3], srcl);
        int rr = l16 & 3;
        float smq = (rr == 0) ? d0 : (rr == 1) ? d1 : (rr == 2) ? d2 : d3;
        float invq = 1.0f / smq;  // sm >= 1 (max term present)
        const int q = wave * 16 + l16;
        const int qy = q >> 3, qx = q & 7;
        const size_t obase =
            ((size_t)(b * 4096) + (wi * 8 + qy) * 64 + (wj * 8 + qx)) * 256 + head * 32;
#pragma unroll
        for (int nt = 0; nt < 2; nt++) {
            uint2 pk;
            pk.x = cvtpk(ob[nt][0] * invq, ob[nt][1] * invq);
            pk.y = cvtpk(ob[nt][2] * invq, ob[nt][3] * invq);
            *(uint2*)(Op + obase + nt * 16 + quad * 4) = pk;
        }
    }
}

// ---------------------------------------------------------------------------
// Shared 128x128 GEMM mainloop (used by gemm_out).
// ---------------------------------------------------------------------------
__device__ __forceinline__ void gemm_loop(const u16* __restrict__ A,
                                          const u16* __restrict__ B,
                                          int K, int bm, int bn,
                                          u16* sA, u16* sB, f32x4_t acc[4][4]) {
    const int tid  = threadIdx.x;
    const int lane = tid & 63, wave = tid >> 6;
    const int quad = lane >> 4, l16 = lane & 15;
    const int wm = (wave >> 1) * 64, wn = (wave & 1) * 64;

    const int sub = lane >> 3;
    const int cpw = (lane & 7) ^ sub;
    const u16* gA[4]; const u16* gB[4];
    const u16* lA[4]; const u16* lB[4];
#pragma unroll
    for (int i = 0; i < 4; i++) {
        int r8 = (wave * 4 + i) * 8;
        gA[i] = A + ((size_t)(bm * 128 + r8 + sub)) * K + cpw * 8;
        gB[i] = B + ((size_t)(bn * 128 + r8 + sub)) * K + cpw * 8;
        lA[i] = sA + r8 * 64;
        lB[i] = sB + r8 * 64;
    }

    for (int kt = 0; kt < K; kt += 64) {
        __syncthreads();
#pragma unroll
        for (int i = 0; i < 4; i++) gload16(gA[i] + kt, lA[i]);
#pragma unroll
        for (int i = 0; i < 4; i++) gload16(gB[i] + kt, lB[i]);
        __syncthreads();
#pragma unroll
        for (int ks = 0; ks < 2; ks++) {
            bf16x8_t af[4], bg[4];
#pragma unroll
            for (int i = 0; i < 4; i++) {
                int row = wm + i * 16 + l16;
                int cp = (ks * 4 + quad) ^ (row & 7);
                af[i] = *(const bf16x8_t*)(sA + row * 64 + cp * 8);
            }
#pragma unroll
            for (int j = 0; j < 4; j++) {
                int row = wn + j * 16 + l16;
                int cp = (ks * 4 + quad) ^ (row & 7);
                bg[j] = *(const bf16x8_t*)(sB + row * 64 + cp * 8);
            }
#pragma unroll
            for (int i = 0; i < 4; i++)
#pragma unroll
                for (int j = 0; j < 4; j++)
                    acc[i][j] = MFMA16(af[i], bg[j], acc[i][j]);
        }
    }
}

// ---------------------------------------------------------------------------
// Kernel 3: y = attn @ W2^T + b2 -> d_out [b][c'][hw]; fp32 if fp32 inputs.
// ---------------------------------------------------------------------------
__global__ __launch_bounds__(256) void gemm_out(const u16* __restrict__ xu,
                                                const u16* __restrict__ Ap,
                                                const u16* __restrict__ W2,
                                                const u16* __restrict__ b2,
                                                void* __restrict__ Y) {
    __shared__ __align__(16) u16 sA[128 * 64];
    __shared__ __align__(16) u16 sB[128 * 64];
    __shared__ int wcnt[4];
    const u32 out_f32 = detect_fp32(xu, threadIdx.x, wcnt);

    f32x4_t acc[4][4];
    const f32x4_t zz = {0.f, 0.f, 0.f, 0.f};
#pragma unroll
    for (int i = 0; i < 4; i++)
#pragma unroll
        for (int j = 0; j < 4; j++) acc[i][j] = zz;

    const int bm = blockIdx.x, bn = blockIdx.y;
    gemm_loop(Ap, W2, 256, bm, bn, sA, sB, acc);

    const int lane = threadIdx.x & 63, wave = threadIdx.x >> 6;
    const int quad = lane >> 4, l16 = lane & 15;
    const int wm = (wave >> 1) * 64, wn = (wave & 1) * 64;
    const int b = bm >> 5;
    const int hw0 = (bm & 31) * 128;
#pragma unroll
    for (int j = 0; j < 4; j++) {
        int o = bn * 128 + wn + j * 16 + l16;
        float bias = bf2f(b2[o]);
        size_t base = ((size_t)(b * 256 + o)) * 4096;
        if (out_f32) {
            float* Yf = (float*)Y;
#pragma unroll
            for (int i = 0; i < 4; i++) {
                int m0 = hw0 + wm + i * 16 + quad * 4;
                f32x4_t ov;
#pragma unroll
                for (int r = 0; r < 4; r++) ov[r] = acc[i][j][r] + bias;
                *(f32x4_t*)(Yf + base + m0) = ov;
            }
        } else {
            u16* Yh = (u16*)Y;
#pragma unroll
            for (int i = 0; i < 4; i++) {
                int m0 = hw0 + wm + i * 16 + quad * 4;
                uint2 pk;
                pk.x = cvtpk(acc[i][j][0] + bias, acc[i][j][1] + bias);
                pk.y = cvtpk(acc[i][j][2] + bias, acc[i][j][3] + bias);
                *(uint2*)(Yh + base + m0) = pk;
            }
        }
    }
}

// ---------------------------------------------------------------------------
extern "C" void kernel_launch(void* const* d_in, const int* in_sizes, int n_in,
                              void* d_out, int out_size, void* d_ws, size_t ws_size,
                              hipStream_t stream) {
    (void)in_sizes; (void)n_in; (void)out_size; (void)ws_size;
    const void* x  = d_in[0];
    const void* W1 = d_in[1];
    const void* b1 = d_in[2];
    const void* W2 = d_in[3];
    const void* b2 = d_in[4];
    const u16* xu = (const u16*)x;

    char* ws = (char*)d_ws;
    const size_t MB32 = (size_t)32 * 1024 * 1024;
    u16* xT  = (u16*)(ws);              // 32 MiB; reused as attention output Op
    u16* Q2  = (u16*)(ws + MB32);       // 32 MiB  [b][head][hw][e]
    u16* K2  = (u16*)(ws + 2 * MB32);   // 32 MiB
    u16* V2  = (u16*)(ws + 3 * MB32);   // 32 MiB
    u16* W1b = (u16*)(ws + 4 * MB32);   // 196608 elems (grouped-QKV rows)
    u16* b1b = W1b + 196608;            // 768
    u16* W2b = b1b + 768;               // 65536
    u16* b2b = W2b + 65536;             // 256
    u16* Op  = xT;                      // overlay: xT dead after gemm_qkv

    conv_w  <<<1028, 256, 0, stream>>>(xu, W1, b1, W2, b2, W1b, b1b, W2b, b2b);
    conv_x  <<<dim3(64, 4, 16), 256, 0, stream>>>(x, xT);
    gemm_qkv<<<4096, 256, 0, stream>>>(xT, W1b, b1b, Q2, K2, V2);
    attn_kernel<<<dim3(64, 8, 16), 256, 0, stream>>>(Q2, K2, V2, Op);
    gemm_out<<<dim3(512, 2), 256, 0, stream>>>(xu, Op, W2b, b2b, d_out);
}

// Round 10
// 236.224 us; speedup vs baseline: 1.0533x; 1.0311x over previous
//
#include <hip/hip_runtime.h>
#include <stdint.h>

typedef unsigned short u16;
typedef unsigned int   u32;
typedef __bf16 bf16x8_t __attribute__((ext_vector_type(8)));
typedef float  f32x4_t  __attribute__((ext_vector_type(4)));

#define MFMA16(a, b, c) __builtin_amdgcn_mfma_f32_16x16x32_bf16((a), (b), (c), 0, 0, 0)

__device__ __forceinline__ float bf2f(u16 u) {
    union { u32 i; float f; } c; c.i = ((u32)u) << 16; return c.f;
}
__device__ __forceinline__ u16 f2bf(float f) {
    union { float f; u32 i; } c; c.f = f;
    u32 x = c.i;
    return (u16)((x + 0x7fffu + ((x >> 16) & 1u)) >> 16);  // RNE
}
// Packed f32x2 -> bf16x2 (RNE), single instruction. S0 -> bits[15:0].
__device__ __forceinline__ u32 cvtpk(float lo, float hi) {
    u32 r;
    asm("v_cvt_pk_bf16_f32 %0, %1, %2" : "=v"(r) : "v"(lo), "v"(hi));
    return r;
}
// 2^x via v_exp_f32 (builtin avoids glibc __exp2f macro collision).
__device__ __forceinline__ float exp2g(float x) {
    return __builtin_amdgcn_exp2f(x);
}

// Direct global->LDS DMA, 16B per lane. LDS dest must be wave-uniform base
// (HW adds lane*16); global src is per-lane (carries the XOR swizzle).
typedef const unsigned int __attribute__((address_space(1)))* gas_t;
typedef unsigned int __attribute__((address_space(3)))* las_t;
__device__ __forceinline__ void gload16(const u16* g, const u16* l) {
    __builtin_amdgcn_global_load_lds((gas_t)(const void*)g, (las_t)(void*)l, 16, 0, 0);
}

// ---------------------------------------------------------------------------
// Block-local input-dtype detection (flag=1 -> fp32 inputs).
// ---------------------------------------------------------------------------
__device__ __forceinline__ u32 detect_fp32(const u16* __restrict__ xu,
                                           int tid, int* wcnt) {
    u16 w = xu[2 * tid];
    int e = (w >> 7) & 0xff;
    int ok = (e >= 80 && e <= 160) ? 1 : 0;
    unsigned long long m = __ballot(ok);
    if ((tid & 63) == 0) wcnt[tid >> 6] = __popcll(m);
    __syncthreads();
    int cnt = wcnt[0] + wcnt[1] + wcnt[2] + wcnt[3];
    return (cnt < 160) ? 1u : 0u;
}

// ---------------------------------------------------------------------------
// Kernel W: convert W1/b1/W2/b2 to bf16 copies in workspace.
// W1/b1 rows are PERMUTED to grouped-QKV: new row h*96 + w*32 + e comes from
// original row 3*(h*32+e) + w.
// ---------------------------------------------------------------------------
__global__ __launch_bounds__(256) void conv_w(const u16* __restrict__ xu,
                                              const void* __restrict__ W1,
                                              const void* __restrict__ b1,
                                              const void* __restrict__ W2,
                                              const void* __restrict__ b2,
                                              u16* __restrict__ W1b,
                                              u16* __restrict__ b1b,
                                              u16* __restrict__ W2b,
                                              u16* __restrict__ b2b) {
    __shared__ int wcnt[4];
    u32 f = detect_fp32(xu, threadIdx.x, wcnt);
    int i = blockIdx.x * 256 + threadIdx.x;
    const int n1 = 196608, n2 = 768, n3 = 65536;
    if (i < n1) {
        int o = i >> 8, col = i & 255;
        int h = o / 96, rem = o - h * 96;
        int w = rem >> 5, e = rem & 31;
        int src = (3 * (h * 32 + e) + w) * 256 + col;
        W1b[i] = f ? f2bf(((const float*)W1)[src]) : ((const u16*)W1)[src];
    } else if (i < n1 + n2) {
        int o = i - n1;
        int h = o / 96, rem = o - h * 96;
        int w = rem >> 5, e = rem & 31;
        int src = 3 * (h * 32 + e) + w;
        b1b[o] = f ? f2bf(((const float*)b1)[src]) : ((const u16*)b1)[src];
    } else if (i < n1 + n2 + n3) {
        int li = i - n1 - n2;
        W2b[li] = f ? f2bf(((const float*)W2)[li]) : ((const u16*)W2)[li];
    } else {
        int li = i - n1 - n2 - n3;
        b2b[li] = f ? f2bf(((const float*)b2)[li]) : ((const u16*)b2)[li];
    }
}

// ---------------------------------------------------------------------------
// Kernel X: x [b][c][hw] -> xT [b*4096+hw][c] bf16 (pixel-major)
// ---------------------------------------------------------------------------
__global__ __launch_bounds__(256) void conv_x(const void* __restrict__ X,
                                              u16* __restrict__ XT) {
    __shared__ __align__(16) u16 tile[64][68];
    __shared__ int wcnt[4];
    const int tid = threadIdx.x;
    u32 f = detect_fp32((const u16*)X, tid, wcnt);
    const int b = blockIdx.z, c0 = blockIdx.y * 64, h0 = blockIdx.x * 64;
    const int col = tid & 63, rq = tid >> 6;
    if (f) {
        const float* Xf = (const float*)X;
#pragma unroll
        for (int i = 0; i < 16; i++) {
            int row = i * 4 + rq;
            tile[row][col] = f2bf(Xf[((size_t)(b * 256 + c0 + row)) * 4096 + h0 + col]);
        }
    } else {
        const u16* Xh = (const u16*)X;
#pragma unroll
        for (int i = 0; i < 16; i++) {
            int row = i * 4 + rq;
            tile[row][col] = Xh[((size_t)(b * 256 + c0 + row)) * 4096 + h0 + col];
        }
    }
    __syncthreads();
#pragma unroll
    for (int i = 0; i < 16; i++) {
        int row = i * 4 + rq;
        XT[((size_t)(b * 4096 + h0 + row)) * 256 + c0 + col] = tile[col][row];
    }
}

// ---------------------------------------------------------------------------
// Kernel 1: qkv = xT @ W1^T + b1 with 96-wide n-tiles (= one head exactly).
// W1b rows grouped [Q|K|V] per head -> vectorizable repack epilogue.
// ---------------------------------------------------------------------------
__global__ __launch_bounds__(256) void gemm_qkv(const u16* __restrict__ XT,
                                                const u16* __restrict__ W1,
                                                const u16* __restrict__ b1,
                                                u16* __restrict__ Q2,
                                                u16* __restrict__ K2,
                                                u16* __restrict__ V2) {
    __shared__ __align__(16) u16 smem[128 * 64 + 96 * 64];  // 28 KB
    u16* sA = smem;
    u16* sB = smem + 128 * 64;
    u16* Cs = smem;  // reused after barrier: 128 x 104 = 13312 <= 14336

    const int tid  = threadIdx.x;
    const int lane = tid & 63, wave = tid >> 6;
    const int quad = lane >> 4, l16 = lane & 15;
    const int wm = wave * 32;
    const int bx = blockIdx.x;
    const int bm = (bx >> 6) * 8 + (bx & 7);  // 512 m-tiles
    const int h  = (bx >> 3) & 7;             // 8 heads
    const int o_base = h * 96;

    f32x4_t acc[2][6];
    const f32x4_t zz = {0.f, 0.f, 0.f, 0.f};
#pragma unroll
    for (int i = 0; i < 2; i++)
#pragma unroll
        for (int j = 0; j < 6; j++) acc[i][j] = zz;

    // per-lane pre-swizzled staging addresses (k-invariant, hoisted)
    const int sub = lane >> 3;              // row-within-8
    const int cpw = (lane & 7) ^ sub;       // global chunk for this lane
    const u16* gA[4]; const u16* gB[3];
    const u16* lA[4]; const u16* lB[3];
#pragma unroll
    for (int i = 0; i < 4; i++) {
        int r8 = (wave * 4 + i) * 8;
        gA[i] = XT + ((size_t)(bm * 128 + r8 + sub)) * 256 + cpw * 8;
        lA[i] = sA + r8 * 64;               // wave-uniform LDS base
    }
#pragma unroll
    for (int i = 0; i < 3; i++) {
        int r8 = (wave * 3 + i) * 8;
        gB[i] = W1 + ((size_t)(o_base + r8 + sub)) * 256 + cpw * 8;
        lB[i] = sB + r8 * 64;
    }

    for (int kt = 0; kt < 256; kt += 64) {
        __syncthreads();
#pragma unroll
        for (int i = 0; i < 4; i++) gload16(gA[i] + kt, lA[i]);
#pragma unroll
        for (int i = 0; i < 3; i++) gload16(gB[i] + kt, lB[i]);
        __syncthreads();  // implicit vmcnt(0) drains the DMA
#pragma unroll
        for (int ks = 0; ks < 2; ks++) {
            bf16x8_t af[2], bg[6];
#pragma unroll
            for (int i = 0; i < 2; i++) {
                int row = wm + i * 16 + l16;
                int cp = (ks * 4 + quad) ^ (row & 7);
                af[i] = *(const bf16x8_t*)(sA + row * 64 + cp * 8);
            }
#pragma unroll
            for (int j = 0; j < 6; j++) {
                int row = j * 16 + l16;
                int cp = (ks * 4 + quad) ^ (row & 7);
                bg[j] = *(const bf16x8_t*)(sB + row * 64 + cp * 8);
            }
#pragma unroll
            for (int i = 0; i < 2; i++)
#pragma unroll
                for (int j = 0; j < 6; j++)
                    acc[i][j] = MFMA16(af[i], bg[j], acc[i][j]);
        }
    }

    // ---- epilogue: bias + bf16 -> Cs[128 m][col 96] (stride 104) ----
    __syncthreads();
#pragma unroll
    for (int j = 0; j < 6; j++) {
        float bias = bf2f(b1[o_base + j * 16 + l16]);
#pragma unroll
        for (int i = 0; i < 2; i++) {
            int m = wm + i * 16 + quad * 4;
#pragma unroll
            for (int r = 0; r < 4; r++)
                Cs[(m + r) * 104 + j * 16 + l16] = f2bf(acc[i][j][r] + bias);
        }
    }
    __syncthreads();

    // ---- repack: grouped cols -> vector reads; pixel-major [b][h][hw][e] ----
    const int b = bm >> 5;
    const int hw0 = (bm & 31) * 128;
    const size_t hb = ((size_t)(b * 8 + h)) * 4096;
#pragma unroll
    for (int it = 0; it < 2; it++) {
        int u = it * 256 + tid;
        int px = u >> 2, ch = u & 3;
        size_t gaddr = (hb + hw0 + px) * 32 + ch * 8;
        *(uint4*)(Q2 + gaddr) = *(const uint4*)(Cs + px * 104 +      ch * 8);
        *(uint4*)(K2 + gaddr) = *(const uint4*)(Cs + px * 104 + 32 + ch * 8);
        *(uint4*)(V2 + gaddr) = *(const uint4*)(Cs + px * 104 + 64 + ch * 8);
    }
}

// ---------------------------------------------------------------------------
// Kernel 2: windowed overlapping attention (Q 8x8, K/V 12x12 zero-padded).
// FULLY IN-REGISTER P: both MFMAs operand-swapped.
//   QK^T: S^T = mfma(K, Q) -> lane(quad,l16) holds S[k=j*16+quad*4+r][q=l16]
//   softmax: per-lane over 36 k + 2 cross-quad shfl_xor(16/32); lane ends
//            with its own denominator (no gather).
//   PV: P^T B-fragments assembled from packed pk[] via partner-lane shuffles
//       (partner quads 2(quad&1), +1; j = 2kk+(quad>>1)); kk=4 high-quad
//       entries read clamped j=8 garbage that multiplies zeroed Vt cols
//       144..159 -> harmless.
// LDS: Ks 11520 + Vt 10752 = 22272 B -> 7 blocks/CU; ONE barrier total.
// Max-subtraction KEPT (overflow-safe; r5/r6 lesson).
// ---------------------------------------------------------------------------
__global__ __launch_bounds__(256, 6) void attn_kernel(const u16* __restrict__ Q2,
                                                      const u16* __restrict__ K2,
                                                      const u16* __restrict__ V2,
                                                      u16* __restrict__ Op) {
    __shared__ __align__(16) u16 smem[11136];  // 22272 B
    u16* Ks = smem;               // [144][40]
    u16* Vt = smem + 5760;        // [32][168], swizzled cols

    const int tid  = threadIdx.x;
    const int lane = tid & 63, wave = tid >> 6;
    const int quad = lane >> 4, l16 = lane & 15;
    const int win = blockIdx.x, head = blockIdx.y, b = blockIdx.z;
    const int wi = win >> 3, wj = win & 7;
    const size_t hb = ((size_t)(b * 8 + head)) * 4096;

    // ---- Q fragment (B-operand of swapped QK^T): row wave*16+l16 ----
    bf16x8_t aF;
    {
        int px = wave * 16 + l16;
        int qy = px >> 3, qx = px & 7;
        aF = *(const bf16x8_t*)(Q2 + (hb + (wi * 8 + qy) * 64 + wj * 8 + qx) * 32 + quad * 8);
    }
    // ---- stage K + V (merged, one addr calc); V transposed w/ swizzle ----
    for (int u = tid; u < 576; u += 256) {
        int px = u >> 2, ch = u & 3;
        int py = px / 12, kx = px - py * 12;
        int gy = wi * 8 - 2 + py, gx = wj * 8 - 2 + kx;
        uint4 kv = make_uint4(0, 0, 0, 0), vv = make_uint4(0, 0, 0, 0);
        if (gy >= 0 && gy < 64 && gx >= 0 && gx < 64) {
            size_t off = (hb + gy * 64 + gx) * 32 + ch * 8;
            kv = *(const uint4*)(K2 + off);
            vv = *(const uint4*)(V2 + off);
        }
        *(uint4*)(Ks + px * 40 + ch * 8) = kv;
        int colp = px ^ (ch << 3);
        int e0 = ch * 8;
        u32 w0[4] = {vv.x, vv.y, vv.z, vv.w};
#pragma unroll
        for (int p = 0; p < 4; p++) {
            Vt[(e0 + 2 * p    ) * 168 + colp] = (u16)(w0[p] & 0xffff);
            Vt[(e0 + 2 * p + 1) * 168 + colp] = (u16)(w0[p] >> 16);
        }
    }
    // ---- Vt pad cols 144..159 (swizzled addresses) ----
    for (int t = tid; t < 512; t += 256) {
        int e = t >> 4, cl = 144 + (t & 15);
        Vt[e * 168 + (cl ^ ((e >> 3) << 3))] = 0;
    }
    __syncthreads();  // the ONLY barrier

    // ---- S^T = K Q^T: lane holds S[k=j*16+quad*4+r][q=wave*16+l16] ----
    float s[9][4];
    {
        const f32x4_t zz = {0.f, 0.f, 0.f, 0.f};
#pragma unroll
        for (int j = 0; j < 9; j++) {
            bf16x8_t bF = *(const bf16x8_t*)(Ks + (j * 16 + l16) * 40 + quad * 8);
            f32x4_t d = MFMA16(bF, aF, zz);
#pragma unroll
            for (int r = 0; r < 4; r++) s[j][r] = d[r];
        }
    }
    // ---- max over this lane's 36 k (pairwise tree), then cross-quad ----
    float mx;
    {
        float mj[9];
#pragma unroll
        for (int j = 0; j < 9; j++)
            mj[j] = fmaxf(fmaxf(s[j][0], s[j][1]), fmaxf(s[j][2], s[j][3]));
        float t0 = fmaxf(fmaxf(mj[0], mj[1]), fmaxf(mj[2], mj[3]));
        float t1 = fmaxf(fmaxf(mj[4], mj[5]), fmaxf(mj[6], mj[7]));
        mx = fmaxf(fmaxf(t0, t1), mj[8]);
    }
    mx = fmaxf(mx, __shfl_xor(mx, 16));
    mx = fmaxf(mx, __shfl_xor(mx, 32));

    // ---- P^T = exp2((s - mx)*scale2), packed bf16x2 into pk[j][2] ----
    const float scale2 = 0.2550348632705143f;  // log2(e)/sqrt(32)
    const float msc = mx * scale2;
    float s0 = 0.f, s1 = 0.f, s2 = 0.f, s3 = 0.f;
    u32 pk[9][2];
#pragma unroll
    for (int j = 0; j < 9; j++) {
        float p0 = exp2g(fmaf(s[j][0], scale2, -msc));
        float p1 = exp2g(fmaf(s[j][1], scale2, -msc));
        float p2 = exp2g(fmaf(s[j][2], scale2, -msc));
        float p3 = exp2g(fmaf(s[j][3], scale2, -msc));
        s0 += p0; s1 += p1; s2 += p2; s3 += p3;
        pk[j][0] = cvtpk(p0, p1);
        pk[j][1] = cvtpk(p2, p3);
    }
    float sm = (s0 + s1) + (s2 + s3);
    sm += __shfl_xor(sm, 16);
    sm += __shfl_xor(sm, 32);
    const float invq = 1.0f / sm;  // sm >= 1 (max term present)

    // ---- O^T = V^T P^T; B-fragments gathered from partner lanes ----
    const int partA = (2 * (quad & 1)) * 16 + l16;
    const int partB = partA + 16;
    const bool hiQ = quad >= 2;
    f32x4_t ob[2];
    ob[0] = (f32x4_t){0.f, 0.f, 0.f, 0.f};
    ob[1] = (f32x4_t){0.f, 0.f, 0.f, 0.f};
#pragma unroll
    for (int kk = 0; kk < 5; kk++) {
        const int jA = 2 * kk;
        const int jB = (2 * kk + 1 > 8) ? 8 : 2 * kk + 1;
        u32 a0 = __shfl(pk[jA][0], partA), b0 = __shfl(pk[jB][0], partA);
        u32 a1 = __shfl(pk[jA][1], partA), b1 = __shfl(pk[jB][1], partA);
        u32 a2 = __shfl(pk[jA][0], partB), b2 = __shfl(pk[jB][0], partB);
        u32 a3 = __shfl(pk[jA][1], partB), b3 = __shfl(pk[jB][1], partB);
        union { u32 u[4]; bf16x8_t v; } pb;
        pb.u[0] = hiQ ? b0 : a0;
        pb.u[1] = hiQ ? b1 : a1;
        pb.u[2] = hiQ ? b2 : a2;
        pb.u[3] = hiQ ? b3 : a3;
#pragma unroll
        for (int nt = 0; nt < 2; nt++) {
            int er = nt * 16 + l16;
            int sw = (er >> 3) << 3;
            bf16x8_t bV = *(const bf16x8_t*)(Vt + er * 168 + ((kk * 32 + quad * 8) ^ sw));
            ob[nt] = MFMA16(bV, pb.v, ob[nt]);  // D[e_local=quad*4+r][q=l16]
        }
    }
    // ---- epilogue: lane owns q=wave*16+l16, e=nt*16+quad*4..+3 ----
    {
        const int q = wave * 16 + l16;
        const int qy = q >> 3, qx = q & 7;
        const size_t obase =
            ((size_t)(b * 4096) + (wi * 8 + qy) * 64 + (wj * 8 + qx)) * 256 + head * 32;
#pragma unroll
        for (int nt = 0; nt < 2; nt++) {
            uint2 pkk;
            pkk.x = cvtpk(ob[nt][0] * invq, ob[nt][1] * invq);
            pkk.y = cvtpk(ob[nt][2] * invq, ob[nt][3] * invq);
            *(uint2*)(Op + obase + nt * 16 + quad * 4) = pkk;
        }
    }
}

// ---------------------------------------------------------------------------
// Shared 128x128 GEMM mainloop (used by gemm_out).
// ---------------------------------------------------------------------------
__device__ __forceinline__ void gemm_loop(const u16* __restrict__ A,
                                          const u16* __restrict__ B,
                                          int K, int bm, int bn,
                                          u16* sA, u16* sB, f32x4_t acc[4][4]) {
    const int tid  = threadIdx.x;
    const int lane = tid & 63, wave = tid >> 6;
    const int quad = lane >> 4, l16 = lane & 15;
    const int wm = (wave >> 1) * 64, wn = (wave & 1) * 64;

    const int sub = lane >> 3;
    const int cpw = (lane & 7) ^ sub;
    const u16* gA[4]; const u16* gB[4];
    const u16* lA[4]; const u16* lB[4];
#pragma unroll
    for (int i = 0; i < 4; i++) {
        int r8 = (wave * 4 + i) * 8;
        gA[i] = A + ((size_t)(bm * 128 + r8 + sub)) * K + cpw * 8;
        gB[i] = B + ((size_t)(bn * 128 + r8 + sub)) * K + cpw * 8;
        lA[i] = sA + r8 * 64;
        lB[i] = sB + r8 * 64;
    }

    for (int kt = 0; kt < K; kt += 64) {
        __syncthreads();
#pragma unroll
        for (int i = 0; i < 4; i++) gload16(gA[i] + kt, lA[i]);
#pragma unroll
        for (int i = 0; i < 4; i++) gload16(gB[i] + kt, lB[i]);
        __syncthreads();
#pragma unroll
        for (int ks = 0; ks < 2; ks++) {
            bf16x8_t af[4], bg[4];
#pragma unroll
            for (int i = 0; i < 4; i++) {
                int row = wm + i * 16 + l16;
                int cp = (ks * 4 + quad) ^ (row & 7);
                af[i] = *(const bf16x8_t*)(sA + row * 64 + cp * 8);
            }
#pragma unroll
            for (int j = 0; j < 4; j++) {
                int row = wn + j * 16 + l16;
                int cp = (ks * 4 + quad) ^ (row & 7);
                bg[j] = *(const bf16x8_t*)(sB + row * 64 + cp * 8);
            }
#pragma unroll
            for (int i = 0; i < 4; i++)
#pragma unroll
                for (int j = 0; j < 4; j++)
                    acc[i][j] = MFMA16(af[i], bg[j], acc[i][j]);
        }
    }
}

// ---------------------------------------------------------------------------
// Kernel 3: y = attn @ W2^T + b2 -> d_out [b][c'][hw]; fp32 if fp32 inputs.
// ---------------------------------------------------------------------------
__global__ __launch_bounds__(256) void gemm_out(const u16* __restrict__ xu,
                                                const u16* __restrict__ Ap,
                                                const u16* __restrict__ W2,
                                                const u16* __restrict__ b2,
                                                void* __restrict__ Y) {
    __shared__ __align__(16) u16 sA[128 * 64];
    __shared__ __align__(16) u16 sB[128 * 64];
    __shared__ int wcnt[4];
    const u32 out_f32 = detect_fp32(xu, threadIdx.x, wcnt);

    f32x4_t acc[4][4];
    const f32x4_t zz = {0.f, 0.f, 0.f, 0.f};
#pragma unroll
    for (int i = 0; i < 4; i++)
#pragma unroll
        for (int j = 0; j < 4; j++) acc[i][j] = zz;

    const int bm = blockIdx.x, bn = blockIdx.y;
    gemm_loop(Ap, W2, 256, bm, bn, sA, sB, acc);

    const int lane = threadIdx.x & 63, wave = threadIdx.x >> 6;
    const int quad = lane >> 4, l16 = lane & 15;
    const int wm = (wave >> 1) * 64, wn = (wave & 1) * 64;
    const int b = bm >> 5;
    const int hw0 = (bm & 31) * 128;
#pragma unroll
    for (int j = 0; j < 4; j++) {
        int o = bn * 128 + wn + j * 16 + l16;
        float bias = bf2f(b2[o]);
        size_t base = ((size_t)(b * 256 + o)) * 4096;
        if (out_f32) {
            float* Yf = (float*)Y;
#pragma unroll
            for (int i = 0; i < 4; i++) {
                int m0 = hw0 + wm + i * 16 + quad * 4;
                f32x4_t ov;
#pragma unroll
                for (int r = 0; r < 4; r++) ov[r] = acc[i][j][r] + bias;
                *(f32x4_t*)(Yf + base + m0) = ov;
            }
        } else {
            u16* Yh = (u16*)Y;
#pragma unroll
            for (int i = 0; i < 4; i++) {
                int m0 = hw0 + wm + i * 16 + quad * 4;
                uint2 pk;
                pk.x = cvtpk(acc[i][j][0] + bias, acc[i][j][1] + bias);
                pk.y = cvtpk(acc[i][j][2] + bias, acc[i][j][3] + bias);
                *(uint2*)(Yh + base + m0) = pk;
            }
        }
    }
}

// ---------------------------------------------------------------------------
extern "C" void kernel_launch(void* const* d_in, const int* in_sizes, int n_in,
                              void* d_out, int out_size, void* d_ws, size_t ws_size,
                              hipStream_t stream) {
    (void)in_sizes; (void)n_in; (void)out_size; (void)ws_size;
    const void* x  = d_in[0];
    const void* W1 = d_in[1];
    const void* b1 = d_in[2];
    const void* W2 = d_in[3];
    const void* b2 = d_in[4];
    const u16* xu = (const u16*)x;

    char* ws = (char*)d_ws;
    const size_t MB32 = (size_t)32 * 1024 * 1024;
    u16* xT  = (u16*)(ws);              // 32 MiB; reused as attention output Op
    u16* Q2  = (u16*)(ws + MB32);       // 32 MiB  [b][head][hw][e]
    u16* K2  = (u16*)(ws + 2 * MB32);   // 32 MiB
    u16* V2  = (u16*)(ws + 3 * MB32);   // 32 MiB
    u16* W1b = (u16*)(ws + 4 * MB32);   // 196608 elems (grouped-QKV rows)
    u16* b1b = W1b + 196608;            // 768
    u16* W2b = b1b + 768;               // 65536
    u16* b2b = W2b + 65536;             // 256
    u16* Op  = xT;                      // overlay: xT dead after gemm_qkv

    conv_w  <<<1028, 256, 0, stream>>>(xu, W1, b1, W2, b2, W1b, b1b, W2b, b2b);
    conv_x  <<<dim3(64, 4, 16), 256, 0, stream>>>(x, xT);
    gemm_qkv<<<4096, 256, 0, stream>>>(xT, W1b, b1b, Q2, K2, V2);
    attn_kernel<<<dim3(64, 8, 16), 256, 0, stream>>>(Q2, K2, V2, Op);
    gemm_out<<<dim3(512, 2), 256, 0, stream>>>(xu, Op, W2b, b2b, d_out);
}

// Round 13
// 234.025 us; speedup vs baseline: 1.0632x; 1.0094x over previous
//
#include <hip/hip_runtime.h>
#include <stdint.h>

typedef unsigned short u16;
typedef unsigned int   u32;
typedef __bf16 bf16x8_t __attribute__((ext_vector_type(8)));
typedef float  f32x4_t  __attribute__((ext_vector_type(4)));

#define MFMA16(a, b, c) __builtin_amdgcn_mfma_f32_16x16x32_bf16((a), (b), (c), 0, 0, 0)

__device__ __forceinline__ float bf2f(u16 u) {
    union { u32 i; float f; } c; c.i = ((u32)u) << 16; return c.f;
}
__device__ __forceinline__ u16 f2bf(float f) {
    union { float f; u32 i; } c; c.f = f;
    u32 x = c.i;
    return (u16)((x + 0x7fffu + ((x >> 16) & 1u)) >> 16);  // RNE
}
// Packed f32x2 -> bf16x2 (RNE), single instruction. S0 -> bits[15:0].
__device__ __forceinline__ u32 cvtpk(float lo, float hi) {
    u32 r;
    asm("v_cvt_pk_bf16_f32 %0, %1, %2" : "=v"(r) : "v"(lo), "v"(hi));
    return r;
}
// 2^x via v_exp_f32 (builtin avoids glibc __exp2f macro collision).
__device__ __forceinline__ float exp2g(float x) {
    return __builtin_amdgcn_exp2f(x);
}

// Direct global->LDS DMA, 16B per lane. LDS dest must be wave-uniform base
// (HW adds lane*16); global src is per-lane (carries the XOR swizzle).
typedef const unsigned int __attribute__((address_space(1)))* gas_t;
typedef unsigned int __attribute__((address_space(3)))* las_t;
__device__ __forceinline__ void gload16(const u16* g, const u16* l) {
    __builtin_amdgcn_global_load_lds((gas_t)(const void*)g, (las_t)(void*)l, 16, 0, 0);
}

// ---------------------------------------------------------------------------
// Block-local input-dtype detection (flag=1 -> fp32 inputs).
// ---------------------------------------------------------------------------
__device__ __forceinline__ u32 detect_fp32(const u16* __restrict__ xu,
                                           int tid, int* wcnt) {
    u16 w = xu[2 * tid];
    int e = (w >> 7) & 0xff;
    int ok = (e >= 80 && e <= 160) ? 1 : 0;
    unsigned long long m = __ballot(ok);
    if ((tid & 63) == 0) wcnt[tid >> 6] = __popcll(m);
    __syncthreads();
    int cnt = wcnt[0] + wcnt[1] + wcnt[2] + wcnt[3];
    return (cnt < 160) ? 1u : 0u;
}

// ---------------------------------------------------------------------------
// Kernel W: convert W1/b1/W2/b2 to bf16 copies in workspace.
// W1/b1 rows are PERMUTED to grouped-QKV: new row h*96 + w*32 + e comes from
// original row 3*(h*32+e) + w.
// ---------------------------------------------------------------------------
__global__ __launch_bounds__(256) void conv_w(const u16* __restrict__ xu,
                                              const void* __restrict__ W1,
                                              const void* __restrict__ b1,
                                              const void* __restrict__ W2,
                                              const void* __restrict__ b2,
                                              u16* __restrict__ W1b,
                                              u16* __restrict__ b1b,
                                              u16* __restrict__ W2b,
                                              u16* __restrict__ b2b) {
    __shared__ int wcnt[4];
    u32 f = detect_fp32(xu, threadIdx.x, wcnt);
    int i = blockIdx.x * 256 + threadIdx.x;
    const int n1 = 196608, n2 = 768, n3 = 65536;
    if (i < n1) {
        int o = i >> 8, col = i & 255;
        int h = o / 96, rem = o - h * 96;
        int w = rem >> 5, e = rem & 31;
        int src = (3 * (h * 32 + e) + w) * 256 + col;
        W1b[i] = f ? f2bf(((const float*)W1)[src]) : ((const u16*)W1)[src];
    } else if (i < n1 + n2) {
        int o = i - n1;
        int h = o / 96, rem = o - h * 96;
        int w = rem >> 5, e = rem & 31;
        int src = 3 * (h * 32 + e) + w;
        b1b[o] = f ? f2bf(((const float*)b1)[src]) : ((const u16*)b1)[src];
    } else if (i < n1 + n2 + n3) {
        int li = i - n1 - n2;
        W2b[li] = f ? f2bf(((const float*)W2)[li]) : ((const u16*)W2)[li];
    } else {
        int li = i - n1 - n2 - n3;
        b2b[li] = f ? f2bf(((const float*)b2)[li]) : ((const u16*)b2)[li];
    }
}

// ---------------------------------------------------------------------------
// Kernel X: x [b][c][hw] -> xT [b*4096+hw][c] bf16 (pixel-major)
// ---------------------------------------------------------------------------
__global__ __launch_bounds__(256) void conv_x(const void* __restrict__ X,
                                              u16* __restrict__ XT) {
    __shared__ __align__(16) u16 tile[64][68];
    __shared__ int wcnt[4];
    const int tid = threadIdx.x;
    u32 f = detect_fp32((const u16*)X, tid, wcnt);
    const int b = blockIdx.z, c0 = blockIdx.y * 64, h0 = blockIdx.x * 64;
    const int col = tid & 63, rq = tid >> 6;
    if (f) {
        const float* Xf = (const float*)X;
#pragma unroll
        for (int i = 0; i < 16; i++) {
            int row = i * 4 + rq;
            tile[row][col] = f2bf(Xf[((size_t)(b * 256 + c0 + row)) * 4096 + h0 + col]);
        }
    } else {
        const u16* Xh = (const u16*)X;
#pragma unroll
        for (int i = 0; i < 16; i++) {
            int row = i * 4 + rq;
            tile[row][col] = Xh[((size_t)(b * 256 + c0 + row)) * 4096 + h0 + col];
        }
    }
    __syncthreads();
#pragma unroll
    for (int i = 0; i < 16; i++) {
        int row = i * 4 + rq;
        XT[((size_t)(b * 4096 + h0 + row)) * 256 + c0 + col] = tile[col][row];
    }
}

// ---------------------------------------------------------------------------
// Kernel 1: qkv = xT @ W1^T + b1 with 96-wide n-tiles (= one head exactly).
// W1b rows grouped [Q|K|V] per head.  K-loop MFMA is OPERAND-SWAPPED:
// D^T[e_local=quad*4+r][px=l16] -> lane holds 4 consecutive features of one
// pixel -> epilogue is 2 cvtpk + 1 uint2 direct global store per (i,j).
// No Cs LDS round-trip, no epilogue barriers.
// ---------------------------------------------------------------------------
__global__ __launch_bounds__(256) void gemm_qkv(const u16* __restrict__ XT,
                                                const u16* __restrict__ W1,
                                                const u16* __restrict__ b1,
                                                u16* __restrict__ Q2,
                                                u16* __restrict__ K2,
                                                u16* __restrict__ V2) {
    __shared__ __align__(16) u16 smem[128 * 64 + 96 * 64];  // 28 KB
    u16* sA = smem;
    u16* sB = smem + 128 * 64;

    const int tid  = threadIdx.x;
    const int lane = tid & 63, wave = tid >> 6;
    const int quad = lane >> 4, l16 = lane & 15;
    const int wm = wave * 32;
    const int bx = blockIdx.x;
    const int bm = (bx >> 6) * 8 + (bx & 7);  // 512 m-tiles
    const int h  = (bx >> 3) & 7;             // 8 heads
    const int o_base = h * 96;

    f32x4_t acc[2][6];
    const f32x4_t zz = {0.f, 0.f, 0.f, 0.f};
#pragma unroll
    for (int i = 0; i < 2; i++)
#pragma unroll
        for (int j = 0; j < 6; j++) acc[i][j] = zz;

    // per-lane pre-swizzled staging addresses (k-invariant, hoisted)
    const int sub = lane >> 3;              // row-within-8
    const int cpw = (lane & 7) ^ sub;       // global chunk for this lane
    const u16* gA[4]; const u16* gB[3];
    const u16* lA[4]; const u16* lB[3];
#pragma unroll
    for (int i = 0; i < 4; i++) {
        int r8 = (wave * 4 + i) * 8;
        gA[i] = XT + ((size_t)(bm * 128 + r8 + sub)) * 256 + cpw * 8;
        lA[i] = sA + r8 * 64;               // wave-uniform LDS base
    }
#pragma unroll
    for (int i = 0; i < 3; i++) {
        int r8 = (wave * 3 + i) * 8;
        gB[i] = W1 + ((size_t)(o_base + r8 + sub)) * 256 + cpw * 8;
        lB[i] = sB + r8 * 64;
    }

    for (int kt = 0; kt < 256; kt += 64) {
        __syncthreads();
#pragma unroll
        for (int i = 0; i < 4; i++) gload16(gA[i] + kt, lA[i]);
#pragma unroll
        for (int i = 0; i < 3; i++) gload16(gB[i] + kt, lB[i]);
        __syncthreads();  // implicit vmcnt(0) drains the DMA
#pragma unroll
        for (int ks = 0; ks < 2; ks++) {
            bf16x8_t af[2], bg[6];
#pragma unroll
            for (int i = 0; i < 2; i++) {
                int row = wm + i * 16 + l16;
                int cp = (ks * 4 + quad) ^ (row & 7);
                af[i] = *(const bf16x8_t*)(sA + row * 64 + cp * 8);
            }
#pragma unroll
            for (int j = 0; j < 6; j++) {
                int row = j * 16 + l16;
                int cp = (ks * 4 + quad) ^ (row & 7);
                bg[j] = *(const bf16x8_t*)(sB + row * 64 + cp * 8);
            }
#pragma unroll
            for (int i = 0; i < 2; i++)
#pragma unroll
                for (int j = 0; j < 6; j++)
                    acc[i][j] = MFMA16(bg[j], af[i], acc[i][j]);  // swapped: D^T
        }
    }

    // ---- epilogue: direct stores.  Lane holds e = j*16+quad*4+..+3 of
    // pixel px = wm+i*16+l16.  Grouped cols: j<2 -> Q, j<4 -> K, else V. ----
    const int b = bm >> 5;
    const int hw0 = (bm & 31) * 128;
    const size_t hb = ((size_t)(b * 8 + h)) * 4096;
#pragma unroll
    for (int j = 0; j < 6; j++) {
        u16 bb[4];
        *(uint2*)bb = *(const uint2*)(b1 + o_base + j * 16 + quad * 4);
        float bv0 = bf2f(bb[0]), bv1 = bf2f(bb[1]);
        float bv2 = bf2f(bb[2]), bv3 = bf2f(bb[3]);
        u16* dst = (j < 2) ? Q2 : (j < 4) ? K2 : V2;
        const int e0 = (j & 1) * 16 + quad * 4;
#pragma unroll
        for (int i = 0; i < 2; i++) {
            int px = wm + i * 16 + l16;
            size_t gaddr = (hb + hw0 + px) * 32 + e0;
            uint2 st;
            st.x = cvtpk(acc[i][j][0] + bv0, acc[i][j][1] + bv1);
            st.y = cvtpk(acc[i][j][2] + bv2, acc[i][j][3] + bv3);
            *(uint2*)(dst + gaddr) = st;
        }
    }
}

// ---------------------------------------------------------------------------
// Kernel 2: windowed overlapping attention (Q 8x8, K/V 12x12 zero-padded).
// FULLY IN-REGISTER P: both MFMAs operand-swapped.
//   QK^T: S^T = mfma(K, Q) -> lane(quad,l16) holds S[k=j*16+quad*4+r][q=l16]
//   softmax: per-lane over 36 k + 2 cross-quad shfl_xor(16/32); lane ends
//            with its own denominator (no gather).
//   PV: P^T B-fragments assembled from packed pk[] via partner-lane shuffles
//       (partner quads 2(quad&1), +1; j = 2kk+(quad>>1)); kk=4 high-quad
//       entries read clamped j=8 garbage that multiplies zeroed Vt cols
//       144..159 -> harmless.
// LDS: Ks 11520 + Vt 10752 = 22272 B -> 7 blocks/CU; ONE barrier total.
// Max-subtraction KEPT (overflow-safe; r5/r6 lesson).
// ---------------------------------------------------------------------------
__global__ __launch_bounds__(256, 6) void attn_kernel(const u16* __restrict__ Q2,
                                                      const u16* __restrict__ K2,
                                                      const u16* __restrict__ V2,
                                                      u16* __restrict__ Op) {
    __shared__ __align__(16) u16 smem[11136];  // 22272 B
    u16* Ks = smem;               // [144][40]
    u16* Vt = smem + 5760;        // [32][168], swizzled cols

    const int tid  = threadIdx.x;
    const int lane = tid & 63, wave = tid >> 6;
    const int quad = lane >> 4, l16 = lane & 15;
    const int win = blockIdx.x, head = blockIdx.y, b = blockIdx.z;
    const int wi = win >> 3, wj = win & 7;
    const size_t hb = ((size_t)(b * 8 + head)) * 4096;

    // ---- Q fragment (B-operand of swapped QK^T): row wave*16+l16 ----
    bf16x8_t aF;
    {
        int px = wave * 16 + l16;
        int qy = px >> 3, qx = px & 7;
        aF = *(const bf16x8_t*)(Q2 + (hb + (wi * 8 + qy) * 64 + wj * 8 + qx) * 32 + quad * 8);
    }
    // ---- stage K + V (merged, one addr calc); V transposed w/ swizzle ----
    for (int u = tid; u < 576; u += 256) {
        int px = u >> 2, ch = u & 3;
        int py = px / 12, kx = px - py * 12;
        int gy = wi * 8 - 2 + py, gx = wj * 8 - 2 + kx;
        uint4 kv = make_uint4(0, 0, 0, 0), vv = make_uint4(0, 0, 0, 0);
        if (gy >= 0 && gy < 64 && gx >= 0 && gx < 64) {
            size_t off = (hb + gy * 64 + gx) * 32 + ch * 8;
            kv = *(const uint4*)(K2 + off);
            vv = *(const uint4*)(V2 + off);
        }
        *(uint4*)(Ks + px * 40 + ch * 8) = kv;
        int colp = px ^ (ch << 3);
        int e0 = ch * 8;
        u32 w0[4] = {vv.x, vv.y, vv.z, vv.w};
#pragma unroll
        for (int p = 0; p < 4; p++) {
            Vt[(e0 + 2 * p    ) * 168 + colp] = (u16)(w0[p] & 0xffff);
            Vt[(e0 + 2 * p + 1) * 168 + colp] = (u16)(w0[p] >> 16);
        }
    }
    // ---- Vt pad cols 144..159 (swizzled addresses) ----
    for (int t = tid; t < 512; t += 256) {
        int e = t >> 4, cl = 144 + (t & 15);
        Vt[e * 168 + (cl ^ ((e >> 3) << 3))] = 0;
    }
    __syncthreads();  // the ONLY barrier

    // ---- S^T = K Q^T: lane holds S[k=j*16+quad*4+r][q=wave*16+l16] ----
    float s[9][4];
    {
        const f32x4_t zz = {0.f, 0.f, 0.f, 0.f};
#pragma unroll
        for (int j = 0; j < 9; j++) {
            bf16x8_t bF = *(const bf16x8_t*)(Ks + (j * 16 + l16) * 40 + quad * 8);
            f32x4_t d = MFMA16(bF, aF, zz);
#pragma unroll
            for (int r = 0; r < 4; r++) s[j][r] = d[r];
        }
    }
    // ---- max over this lane's 36 k (pairwise tree), then cross-quad ----
    float mx;
    {
        float mj[9];
#pragma unroll
        for (int j = 0; j < 9; j++)
            mj[j] = fmaxf(fmaxf(s[j][0], s[j][1]), fmaxf(s[j][2], s[j][3]));
        float t0 = fmaxf(fmaxf(mj[0], mj[1]), fmaxf(mj[2], mj[3]));
        float t1 = fmaxf(fmaxf(mj[4], mj[5]), fmaxf(mj[6], mj[7]));
        mx = fmaxf(fmaxf(t0, t1), mj[8]);
    }
    mx = fmaxf(mx, __shfl_xor(mx, 16));
    mx = fmaxf(mx, __shfl_xor(mx, 32));

    // ---- P^T = exp2((s - mx)*scale2), packed bf16x2 into pk[j][2] ----
    const float scale2 = 0.2550348632705143f;  // log2(e)/sqrt(32)
    const float msc = mx * scale2;
    float s0 = 0.f, s1 = 0.f, s2 = 0.f, s3 = 0.f;
    u32 pk[9][2];
#pragma unroll
    for (int j = 0; j < 9; j++) {
        float p0 = exp2g(fmaf(s[j][0], scale2, -msc));
        float p1 = exp2g(fmaf(s[j][1], scale2, -msc));
        float p2 = exp2g(fmaf(s[j][2], scale2, -msc));
        float p3 = exp2g(fmaf(s[j][3], scale2, -msc));
        s0 += p0; s1 += p1; s2 += p2; s3 += p3;
        pk[j][0] = cvtpk(p0, p1);
        pk[j][1] = cvtpk(p2, p3);
    }
    float sm = (s0 + s1) + (s2 + s3);
    sm += __shfl_xor(sm, 16);
    sm += __shfl_xor(sm, 32);
    const float invq = 1.0f / sm;  // sm >= 1 (max term present)

    // ---- O^T = V^T P^T; B-fragments gathered from partner lanes ----
    const int partA = (2 * (quad & 1)) * 16 + l16;
    const int partB = partA + 16;
    const bool hiQ = quad >= 2;
    f32x4_t ob[2];
    ob[0] = (f32x4_t){0.f, 0.f, 0.f, 0.f};
    ob[1] = (f32x4_t){0.f, 0.f, 0.f, 0.f};
#pragma unroll
    for (int kk = 0; kk < 5; kk++) {
        const int jA = 2 * kk;
        const int jB = (2 * kk + 1 > 8) ? 8 : 2 * kk + 1;
        u32 a0 = __shfl(pk[jA][0], partA), b0 = __shfl(pk[jB][0], partA);
        u32 a1 = __shfl(pk[jA][1], partA), b1 = __shfl(pk[jB][1], partA);
        u32 a2 = __shfl(pk[jA][0], partB), b2 = __shfl(pk[jB][0], partB);
        u32 a3 = __shfl(pk[jA][1], partB), b3 = __shfl(pk[jB][1], partB);
        union { u32 u[4]; bf16x8_t v; } pb;
        pb.u[0] = hiQ ? b0 : a0;
        pb.u[1] = hiQ ? b1 : a1;
        pb.u[2] = hiQ ? b2 : a2;
        pb.u[3] = hiQ ? b3 : a3;
#pragma unroll
        for (int nt = 0; nt < 2; nt++) {
            int er = nt * 16 + l16;
            int sw = (er >> 3) << 3;
            bf16x8_t bV = *(const bf16x8_t*)(Vt + er * 168 + ((kk * 32 + quad * 8) ^ sw));
            ob[nt] = MFMA16(bV, pb.v, ob[nt]);  // D[e_local=quad*4+r][q=l16]
        }
    }
    // ---- epilogue: lane owns q=wave*16+l16, e=nt*16+quad*4..+3 ----
    {
        const int q = wave * 16 + l16;
        const int qy = q >> 3, qx = q & 7;
        const size_t obase =
            ((size_t)(b * 4096) + (wi * 8 + qy) * 64 + (wj * 8 + qx)) * 256 + head * 32;
#pragma unroll
        for (int nt = 0; nt < 2; nt++) {
            uint2 pkk;
            pkk.x = cvtpk(ob[nt][0] * invq, ob[nt][1] * invq);
            pkk.y = cvtpk(ob[nt][2] * invq, ob[nt][3] * invq);
            *(uint2*)(Op + obase + nt * 16 + quad * 4) = pkk;
        }
    }
}

// ---------------------------------------------------------------------------
// Shared 128x128 GEMM mainloop (used by gemm_out).
// ---------------------------------------------------------------------------
__device__ __forceinline__ void gemm_loop(const u16* __restrict__ A,
                                          const u16* __restrict__ B,
                                          int K, int bm, int bn,
                                          u16* sA, u16* sB, f32x4_t acc[4][4]) {
    const int tid  = threadIdx.x;
    const int lane = tid & 63, wave = tid >> 6;
    const int quad = lane >> 4, l16 = lane & 15;
    const int wm = (wave >> 1) * 64, wn = (wave & 1) * 64;

    const int sub = lane >> 3;
    const int cpw = (lane & 7) ^ sub;
    const u16* gA[4]; const u16* gB[4];
    const u16* lA[4]; const u16* lB[4];
#pragma unroll
    for (int i = 0; i < 4; i++) {
        int r8 = (wave * 4 + i) * 8;
        gA[i] = A + ((size_t)(bm * 128 + r8 + sub)) * K + cpw * 8;
        gB[i] = B + ((size_t)(bn * 128 + r8 + sub)) * K + cpw * 8;
        lA[i] = sA + r8 * 64;
        lB[i] = sB + r8 * 64;
    }

    for (int kt = 0; kt < K; kt += 64) {
        __syncthreads();
#pragma unroll
        for (int i = 0; i < 4; i++) gload16(gA[i] + kt, lA[i]);
#pragma unroll
        for (int i = 0; i < 4; i++) gload16(gB[i] + kt, lB[i]);
        __syncthreads();
#pragma unroll
        for (int ks = 0; ks < 2; ks++) {
            bf16x8_t af[4], bg[4];
#pragma unroll
            for (int i = 0; i < 4; i++) {
                int row = wm + i * 16 + l16;
                int cp = (ks * 4 + quad) ^ (row & 7);
                af[i] = *(const bf16x8_t*)(sA + row * 64 + cp * 8);
            }
#pragma unroll
            for (int j = 0; j < 4; j++) {
                int row = wn + j * 16 + l16;
                int cp = (ks * 4 + quad) ^ (row & 7);
                bg[j] = *(const bf16x8_t*)(sB + row * 64 + cp * 8);
            }
#pragma unroll
            for (int i = 0; i < 4; i++)
#pragma unroll
                for (int j = 0; j < 4; j++)
                    acc[i][j] = MFMA16(af[i], bg[j], acc[i][j]);
        }
    }
}

// ---------------------------------------------------------------------------
// Kernel 3: y = attn @ W2^T + b2 -> d_out [b][c'][hw]; fp32 if fp32 inputs.
// ---------------------------------------------------------------------------
__global__ __launch_bounds__(256) void gemm_out(const u16* __restrict__ xu,
                                                const u16* __restrict__ Ap,
                                                const u16* __restrict__ W2,
                                                const u16* __restrict__ b2,
                                                void* __restrict__ Y) {
    __shared__ __align__(16) u16 sA[128 * 64];
    __shared__ __align__(16) u16 sB[128 * 64];
    __shared__ int wcnt[4];
    const u32 out_f32 = detect_fp32(xu, threadIdx.x, wcnt);

    f32x4_t acc[4][4];
    const f32x4_t zz = {0.f, 0.f, 0.f, 0.f};
#pragma unroll
    for (int i = 0; i < 4; i++)
#pragma unroll
        for (int j = 0; j < 4; j++) acc[i][j] = zz;

    const int bm = blockIdx.x, bn = blockIdx.y;
    gemm_loop(Ap, W2, 256, bm, bn, sA, sB, acc);

    const int lane = threadIdx.x & 63, wave = threadIdx.x >> 6;
    const int quad = lane >> 4, l16 = lane & 15;
    const int wm = (wave >> 1) * 64, wn = (wave & 1) * 64;
    const int b = bm >> 5;
    const int hw0 = (bm & 31) * 128;
#pragma unroll
    for (int j = 0; j < 4; j++) {
        int o = bn * 128 + wn + j * 16 + l16;
        float bias = bf2f(b2[o]);
        size_t base = ((size_t)(b * 256 + o)) * 4096;
        if (out_f32) {
            float* Yf = (float*)Y;
#pragma unroll
            for (int i = 0; i < 4; i++) {
                int m0 = hw0 + wm + i * 16 + quad * 4;
                f32x4_t ov;
#pragma unroll
                for (int r = 0; r < 4; r++) ov[r] = acc[i][j][r] + bias;
                *(f32x4_t*)(Yf + base + m0) = ov;
            }
        } else {
            u16* Yh = (u16*)Y;
#pragma unroll
            for (int i = 0; i < 4; i++) {
                int m0 = hw0 + wm + i * 16 + quad * 4;
                uint2 pk;
                pk.x = cvtpk(acc[i][j][0] + bias, acc[i][j][1] + bias);
                pk.y = cvtpk(acc[i][j][2] + bias, acc[i][j][3] + bias);
                *(uint2*)(Yh + base + m0) = pk;
            }
        }
    }
}

// ---------------------------------------------------------------------------
extern "C" void kernel_launch(void* const* d_in, const int* in_sizes, int n_in,
                              void* d_out, int out_size, void* d_ws, size_t ws_size,
                              hipStream_t stream) {
    (void)in_sizes; (void)n_in; (void)out_size; (void)ws_size;
    const void* x  = d_in[0];
    const void* W1 = d_in[1];
    const void* b1 = d_in[2];
    const void* W2 = d_in[3];
    const void* b2 = d_in[4];
    const u16* xu = (const u16*)x;

    char* ws = (char*)d_ws;
    const size_t MB32 = (size_t)32 * 1024 * 1024;
    u16* xT  = (u16*)(ws);              // 32 MiB; reused as attention output Op
    u16* Q2  = (u16*)(ws + MB32);       // 32 MiB  [b][head][hw][e]
    u16* K2  = (u16*)(ws + 2 * MB32);   // 32 MiB
    u16* V2  = (u16*)(ws + 3 * MB32);   // 32 MiB
    u16* W1b = (u16*)(ws + 4 * MB32);   // 196608 elems (grouped-QKV rows)
    u16* b1b = W1b + 196608;            // 768
    u16* W2b = b1b + 768;               // 65536
    u16* b2b = W2b + 65536;             // 256
    u16* Op  = xT;                      // overlay: xT dead after gemm_qkv

    conv_w  <<<1028, 256, 0, stream>>>(xu, W1, b1, W2, b2, W1b, b1b, W2b, b2b);
    conv_x  <<<dim3(64, 4, 16), 256, 0, stream>>>(x, xT);
    gemm_qkv<<<4096, 256, 0, stream>>>(xT, W1b, b1b, Q2, K2, V2);
    attn_kernel<<<dim3(64, 8, 16), 256, 0, stream>>>(Q2, K2, V2, Op);
    gemm_out<<<dim3(512, 2), 256, 0, stream>>>(xu, Op, W2b, b2b, d_out);
}